// Round 6
// baseline (388.330 us; speedup 1.0000x reference)
//
#include <hip/hip_runtime.h>

#define B_N 1024
#define X_N 1024
#define Y_N 16384
#define Z_N 1000
#define GK  2048
#define MARGIN 0.009f

// output float offsets
#define OFF_ACT      0
#define OFF_MAXRESP  1
#define OFF_WX       1025
#define OFF_WZ       16778241
#define OFF_U        33162241
#define OFF_THR      49546241
#define OFF_AGE      49562625
#define OFF_ZAGE     49579009

// scratch placed inside not-yet-written d_out regions (16B aligned byte offsets)
#define SCR_B_BYTES    4112ull       /* Bb bf16 64MB, in OFF_WX region */
#define SCR_S_BYTES    67112992ull   /* Sc bf16 32MB, in OFF_WZ region */
#define SCR_A_BYTES    132648976ull  /* Ab bf16 4MB,  in OFF_U region */
#define SCR_CAND_BYTES 136843296ull  /* u32[1024][512] = 2MB, in OFF_U region */

// ws float offsets
#define WS_INV_X    0
#define WS_INV_WX   1024
#define WS_INV_WZ   17408
#define WS_INV_U    33792
#define WS_FIDX     38912   /* int[1024] */
#define WS_CNT      39936   /* int[16384] */
#define WS_ZCNT     56320   /* int[1024] */
#define WS_SEGMIN   57344   /* uint[16384] */
#define WS_CTR      73728   /* int[8]: [0]=unact_cnt [1]=act_cnt [2]=min_act_idx */
#define WS_MBITS    73736   /* u64[256] */
#define WS_CCNT     74248   /* int[1024] */

typedef unsigned short ushort_t;
typedef __bf16 bf16x8 __attribute__((ext_vector_type(8)));
typedef float f32x4 __attribute__((ext_vector_type(4)));

__device__ __forceinline__ unsigned enc_f(float f) {
    unsigned u = __float_as_uint(f);
    return (u & 0x80000000u) ? ~u : (u | 0x80000000u);
}
__device__ __forceinline__ float dec_f(unsigned e) {
    unsigned u = (e & 0x80000000u) ? (e ^ 0x80000000u) : ~e;
    return __uint_as_float(u);
}
__device__ __forceinline__ unsigned long long pack_vi(float v, int y) {
    return ((unsigned long long)enc_f(v) << 32) |
           (unsigned long long)(0xFFFFFFFFu - (unsigned)y);
}
__device__ __forceinline__ ushort_t f2b(float f) {
    unsigned u = __float_as_uint(f);
    return (ushort_t)((u + 0x7FFFu + ((u >> 16) & 1u)) >> 16);
}
__device__ __forceinline__ float b2f(unsigned lo16) {
    return __uint_as_float(lo16 << 16);
}

#define GLOAD16(gp, lp) __builtin_amdgcn_global_load_lds( \
    (const __attribute__((address_space(1))) void*)(gp),  \
    (__attribute__((address_space(3))) void*)(lp), 16, 0, 0)

__global__ void init_kernel(int* cnt, unsigned* segmin, int* zcnt, int* ctr) {
    int i = blockIdx.x * 256 + threadIdx.x;
    if (i < Y_N) { cnt[i] = 0; segmin[i] = 0xFFFFFFFFu; }
    if (i < 1024) zcnt[i] = 0;
    if (i < 8) ctr[i] = (i == 2) ? 0x7FFFFFFF : 0;
}

__global__ void rownorm_kernel(const float* __restrict__ src, int rowlen,
                               float* __restrict__ inv_out) {
    int row = blockIdx.x;
    const float* p = src + (size_t)row * rowlen;
    float ss = 0.f;
    for (int e = threadIdx.x; e < rowlen; e += 256) { float v = p[e]; ss += v * v; }
    #pragma unroll
    for (int s = 32; s > 0; s >>= 1) ss += __shfl_xor(ss, s, 64);
    __shared__ float red[4];
    if ((threadIdx.x & 63) == 0) red[threadIdx.x >> 6] = ss;
    __syncthreads();
    if (threadIdx.x == 0) {
        float tot = red[0] + red[1] + red[2] + red[3];
        inv_out[row] = 1.0f / fmaxf(sqrtf(tot), 1e-12f);
    }
}

__global__ void unact_kernel(const float* __restrict__ y_age, int* ctr,
                             unsigned long long* __restrict__ mbits) {
    int i = blockIdx.x * 256 + threadIdx.x;
    int a = (y_age[i] < 1.0f) ? 1 : 0;
    unsigned long long m = __ballot(a);
    int mi = a ? 0x7FFFFFFF : i;   // min index over ACTIVATED neurons
    #pragma unroll
    for (int s = 32; s > 0; s >>= 1) mi = min(mi, __shfl_xor(mi, s, 64));
    if ((threadIdx.x & 63) == 0) {
        atomicAdd(ctr, (int)__popcll(m));
        mbits[i >> 6] = m;
        if (mi != 0x7FFFFFFF) atomicMin(&ctr[2], mi);
    }
}

// A [B_N][GK] bf16: cols 0..1023 = 0.5*x_hat ; cols 1024.. = 0.5*one_hot(z)
__global__ void pack_x_kernel(const float* __restrict__ x, const float* __restrict__ inv_x,
                              const int* __restrict__ zlab, ushort_t* __restrict__ A) {
    int i = blockIdx.x * 256 + threadIdx.x;
    int idx = i * 8;
    int bb = idx >> 11;
    int k = idx & (GK - 1);
    ushort_t o[8];
    if (k < X_N) {
        float invx = 0.5f * inv_x[bb];
        const float* xr = x + (size_t)bb * X_N + k;
        #pragma unroll
        for (int j = 0; j < 8; ++j) o[j] = f2b(invx * xr[j]);
    } else {
        int zb = zlab[bb];
        #pragma unroll
        for (int j = 0; j < 8; ++j) o[j] = ((k + j - X_N) == zb) ? (ushort_t)0x3F00 : (ushort_t)0;
    }
    *reinterpret_cast<uint4*>(A + idx) = *reinterpret_cast<uint4*>(o);
}

// fused: row-norms of wxw/wzw + pack B row [Y_N][GK] bf16 (one block per y)
__global__ __launch_bounds__(256) void pack_w_kernel(
    const float* __restrict__ wxw, const float* __restrict__ wzw,
    ushort_t* __restrict__ Bm, float* __restrict__ inv_wx, float* __restrict__ inv_wz) {
    const int y = blockIdx.x, t = threadIdx.x;
    const int lane = t & 63, wid = t >> 6;
    float4 a = reinterpret_cast<const float4*>(wxw + (size_t)y * X_N)[t];
    float4 zv = make_float4(0.f, 0.f, 0.f, 0.f);
    if (t < 250) zv = reinterpret_cast<const float4*>(wzw + (size_t)y * Z_N)[t];
    float s1 = a.x*a.x + a.y*a.y + a.z*a.z + a.w*a.w;
    float s2 = zv.x*zv.x + zv.y*zv.y + zv.z*zv.z + zv.w*zv.w;
    #pragma unroll
    for (int s = 32; s > 0; s >>= 1) {
        s1 += __shfl_xor(s1, s, 64);
        s2 += __shfl_xor(s2, s, 64);
    }
    __shared__ float r1[4], r2[4];
    if (lane == 0) { r1[wid] = s1; r2[wid] = s2; }
    __syncthreads();
    float inv1 = 1.0f / fmaxf(sqrtf(r1[0] + r1[1] + r1[2] + r1[3]), 1e-12f);
    float inv2 = 1.0f / fmaxf(sqrtf(r2[0] + r2[1] + r2[2] + r2[3]), 1e-12f);
    ushort_t o1[4] = { f2b(a.x*inv1), f2b(a.y*inv1), f2b(a.z*inv1), f2b(a.w*inv1) };
    *reinterpret_cast<uint2*>(Bm + (size_t)y * GK + t * 4) = *reinterpret_cast<uint2*>(o1);
    ushort_t o2[4] = { 0, 0, 0, 0 };
    if (t < 250) { o2[0]=f2b(zv.x*inv2); o2[1]=f2b(zv.y*inv2); o2[2]=f2b(zv.z*inv2); o2[3]=f2b(zv.w*inv2); }
    *reinterpret_cast<uint2*>(Bm + (size_t)y * GK + X_N + t * 4) = *reinterpret_cast<uint2*>(o2);
    if (t == 0) { inv_wx[y] = inv1; inv_wz[y] = inv2; }
}

// bf16 MFMA GEMM, m97-style: 128x128 tile, BK=32, 4 waves (2x2), 32KB LDS,
// 3 blocks/CU for cross-block latency hiding. XCD-chunked bid swizzle.
__global__ __launch_bounds__(256, 3) void mm128_kernel(const ushort_t* __restrict__ A,
                                                       const ushort_t* __restrict__ Bm,
                                                       ushort_t* __restrict__ S) {
    // [buf][mat][slot = g*128 + row][8 bf16], g in [0,4) covers BK=32
    __shared__ __align__(16) ushort_t lds[2][2][512][8];
    const int t = threadIdx.x;
    const int wid = t >> 6, lane = t & 63;
    const int bid = blockIdx.x;
    const int lb = (bid & 7) * 128 + (bid >> 3);   // bijective: 1024 % 8 == 0
    const int mt = lb & 7, nt = lb >> 3;
    const int b0 = mt * 128, y0 = nt * 128;
    const int wr = wid >> 1, wc = wid & 1;
    const int r = lane & 15, gq = lane >> 4;

    f32x4 acc[4][4];
    #pragma unroll
    for (int i = 0; i < 4; ++i)
        #pragma unroll
        for (int j = 0; j < 4; ++j) acc[i][j] = (f32x4){0.f, 0.f, 0.f, 0.f};

    auto stage = [&](int buf, int k0) {
        #pragma unroll
        for (int rr = 0; rr < 2; ++rr) {
            int s = rr * 256 + t;          // slot = g*128 + row
            int row = s & 127, g = s >> 7;
            GLOAD16(A  + (size_t)(b0 + row) * GK + k0 + g * 8, &lds[buf][0][s][0]);
            GLOAD16(Bm + (size_t)(y0 + row) * GK + k0 + g * 8, &lds[buf][1][s][0]);
        }
    };

    stage(0, 0);
    __syncthreads();
    int cur = 0;
    for (int ks = 0; ks < GK / 32; ++ks) {
        if (ks < GK / 32 - 1) stage(cur ^ 1, (ks + 1) * 32);
        bf16x8 aF[4], bF[4];
        #pragma unroll
        for (int mf = 0; mf < 4; ++mf)
            aF[mf] = *reinterpret_cast<const bf16x8*>(
                &lds[cur][0][gq * 128 + wr * 64 + mf * 16 + r][0]);
        #pragma unroll
        for (int nf = 0; nf < 4; ++nf)
            bF[nf] = *reinterpret_cast<const bf16x8*>(
                &lds[cur][1][gq * 128 + wc * 64 + nf * 16 + r][0]);
        #pragma unroll
        for (int mf = 0; mf < 4; ++mf)
            #pragma unroll
            for (int nf = 0; nf < 4; ++nf)
                acc[mf][nf] = __builtin_amdgcn_mfma_f32_16x16x32_bf16(
                    aF[mf], bF[nf], acc[mf][nf], 0, 0, 0);
        __syncthreads();
        cur ^= 1;
    }

    // C layout: col = lane&15, row = (lane>>4)*4 + reg
    #pragma unroll
    for (int mf = 0; mf < 4; ++mf) {
        int bg = b0 + wr * 64 + mf * 16 + gq * 4;
        #pragma unroll
        for (int nf = 0; nf < 4; ++nf) {
            int yg = y0 + wc * 64 + nf * 16 + r;
            f32x4 c = acc[mf][nf];
            #pragma unroll
            for (int q = 0; q < 4; ++q)
                S[(size_t)(bg + q) * Y_N + yg] = f2b(c[q]);
        }
    }
}

// per-row: approx max + candidate collection (per-row slab, LDS atomics only)
__global__ __launch_bounds__(256) void scan_kernel(
    const ushort_t* __restrict__ scores, const unsigned long long* __restrict__ mbits,
    const int* __restrict__ ctr, unsigned* __restrict__ gcand, int* __restrict__ ccnt) {
    const int b = blockIdx.x, t = threadIdx.x;
    const int lane = t & 63, wid = t >> 6;
    const uint4* srow = reinterpret_cast<const uint4*>(scores + (size_t)b * Y_N);

    float vmax = -1e30f, mmax = -1e30f;
    for (int c = t; c < Y_N / 8; c += 256) {
        uint4 pk = srow[c];
        int yb = c * 8;
        unsigned m8 = (unsigned)((mbits[yb >> 6] >> (yb & 63)) & 0xFFull);
        unsigned w[4] = {pk.x, pk.y, pk.z, pk.w};
        #pragma unroll
        for (int j = 0; j < 4; ++j) {
            float v0 = b2f(w[j] & 0xFFFFu);
            float v1 = b2f(w[j] >> 16);
            vmax = fmaxf(vmax, fmaxf(v0, v1));
            mmax = fmaxf(mmax, v0 * (float)((m8 >> (2 * j)) & 1u));
            mmax = fmaxf(mmax, v1 * (float)((m8 >> (2 * j + 1)) & 1u));
        }
    }
    #pragma unroll
    for (int s = 32; s > 0; s >>= 1) {
        vmax = fmaxf(vmax, __shfl_xor(vmax, s, 64));
        mmax = fmaxf(mmax, __shfl_xor(mmax, s, 64));
    }
    __shared__ float rv[4], rm[4];
    __shared__ int nA_s, nB_s;
    __shared__ int cA[256], cB[256];
    if (lane == 0) { rv[wid] = vmax; rm[wid] = mmax; }
    if (t == 0) { nA_s = 0; nB_s = 0; }
    __syncthreads();
    float tA = fmaxf(fmaxf(rv[0], rv[1]), fmaxf(rv[2], rv[3])) - MARGIN;
    float tB = fmaxf(fmaxf(rm[0], rm[1]), fmaxf(rm[2], rm[3])) - MARGIN;
    bool anyu = ctr[0] > 0;

    for (int c = t; c < Y_N / 8; c += 256) {
        uint4 pk = srow[c];
        int yb = c * 8;
        unsigned m8 = (unsigned)((mbits[yb >> 6] >> (yb & 63)) & 0xFFull);
        unsigned w[4] = {pk.x, pk.y, pk.z, pk.w};
        #pragma unroll
        for (int j = 0; j < 8; ++j) {
            float v = b2f((j & 1) ? (w[j >> 1] >> 16) : (w[j >> 1] & 0xFFFFu));
            if (v >= tA) { int p = atomicAdd(&nA_s, 1); if (p < 256) cA[p] = yb + j; }
            if (anyu && ((m8 >> j) & 1u) && v >= tB) {
                int p = atomicAdd(&nB_s, 1); if (p < 256) cB[p] = yb + j;
            }
        }
    }
    __syncthreads();
    int nA = min(nA_s, 256), nB = min(nB_s, 256);
    unsigned* slab = gcand + (size_t)b * 512;
    for (int i = t; i < nA; i += 256) slab[i] = (unsigned)cA[i];
    for (int i = t; i < nB; i += 256) slab[256 + i] = (unsigned)cB[i];
    if (t == 0) ccnt[b] = nA | (nB << 16);
}

// per-row: exact fp32 rescore (A list, judge, conditional B list) + finalize
__global__ __launch_bounds__(256) void rescore_kernel(
    const unsigned* __restrict__ gcand, const int* __restrict__ ccnt,
    const float* __restrict__ x, const float* __restrict__ inv_x,
    const float* __restrict__ wxw, const float* __restrict__ inv_wx,
    const float* __restrict__ wzw, const float* __restrict__ inv_wz,
    const int* __restrict__ zlab, const float* __restrict__ y_thr,
    const float* __restrict__ y_age, const int* __restrict__ ctr,
    int* final_idx, int* cnt, unsigned* segmin, int* zcnt,
    float* __restrict__ out_maxresp) {
    const int b = blockIdx.x, t = threadIdx.x;
    const int lane = t & 63, wid = t >> 6;
    int pc = ccnt[b];
    int nA = pc & 0xFFFF, nB = pc >> 16;
    int zb = zlab[b];
    float invx = inv_x[b];
    const unsigned* slab = gcand + (size_t)b * 512;

    const float4* xr = reinterpret_cast<const float4*>(x + (size_t)b * X_N);
    float4 xv[4];
    #pragma unroll
    for (int j = 0; j < 4; ++j) xv[j] = xr[j * 64 + lane];

    __shared__ unsigned long long red[4];
    __shared__ unsigned long long sPM;
    __shared__ int sTakeA;

    // ---- list A (2 candidates per wave-iteration for MLP) ----
    unsigned long long bA = 0ull;
    for (int c = wid; c < nA; c += 8) {
        int y1 = (int)slab[c];
        int c2 = c + 4;
        bool h2 = c2 < nA;
        int y2 = (int)slab[h2 ? c2 : c];
        const float4* w1 = reinterpret_cast<const float4*>(wxw + (size_t)y1 * X_N);
        const float4* w2 = reinterpret_cast<const float4*>(wxw + (size_t)y2 * X_N);
        float d1 = 0.f, d2 = 0.f;
        #pragma unroll
        for (int j = 0; j < 4; ++j) {
            float4 a1 = w1[j * 64 + lane];
            float4 a2 = w2[j * 64 + lane];
            d1 += xv[j].x*a1.x + xv[j].y*a1.y + xv[j].z*a1.z + xv[j].w*a1.w;
            d2 += xv[j].x*a2.x + xv[j].y*a2.y + xv[j].z*a2.z + xv[j].w*a2.w;
        }
        #pragma unroll
        for (int s = 32; s > 0; s >>= 1) {
            d1 += __shfl_xor(d1, s, 64);
            d2 += __shfl_xor(d2, s, 64);
        }
        float v1 = 0.5f*invx*inv_wx[y1]*d1 + 0.5f*inv_wz[y1]*wzw[(size_t)y1*Z_N + zb];
        unsigned long long p1 = pack_vi(v1, y1);
        bA = (p1 > bA) ? p1 : bA;
        if (h2) {
            float v2 = 0.5f*invx*inv_wx[y2]*d2 + 0.5f*inv_wz[y2]*wzw[(size_t)y2*Z_N + zb];
            unsigned long long p2 = pack_vi(v2, y2);
            bA = (p2 > bA) ? p2 : bA;
        }
    }
    if (lane == 0) red[wid] = bA;
    __syncthreads();
    if (t == 0) {
        unsigned long long pm = red[0];
        #pragma unroll
        for (int j = 1; j < 4; ++j) pm = (red[j] > pm) ? red[j] : pm;
        sPM = pm;
        unsigned enc = (unsigned)(pm >> 32);
        int idx = (int)(0xFFFFFFFFu - (unsigned)(pm & 0xFFFFFFFFull));
        float mresp = dec_f(enc);
        out_maxresp[b] = mresp;
        bool judge = (mresp > y_thr[idx]) || (y_age[idx] < 1.0f);
        bool anyu = ctr[0] > 0;
        sTakeA = (judge || !anyu) ? 1 : 0;
    }
    __syncthreads();

    // ---- list B only when fallback needed ----
    if (!sTakeA) {
        unsigned long long bB = 0ull;
        for (int c = wid; c < nB; c += 8) {
            int y1 = (int)slab[256 + c];
            int c2 = c + 4;
            bool h2 = c2 < nB;
            int y2 = (int)slab[256 + (h2 ? c2 : c)];
            const float4* w1 = reinterpret_cast<const float4*>(wxw + (size_t)y1 * X_N);
            const float4* w2 = reinterpret_cast<const float4*>(wxw + (size_t)y2 * X_N);
            float d1 = 0.f, d2 = 0.f;
            #pragma unroll
            for (int j = 0; j < 4; ++j) {
                float4 a1 = w1[j * 64 + lane];
                float4 a2 = w2[j * 64 + lane];
                d1 += xv[j].x*a1.x + xv[j].y*a1.y + xv[j].z*a1.z + xv[j].w*a1.w;
                d2 += xv[j].x*a2.x + xv[j].y*a2.y + xv[j].z*a2.z + xv[j].w*a2.w;
            }
            #pragma unroll
            for (int s = 32; s > 0; s >>= 1) {
                d1 += __shfl_xor(d1, s, 64);
                d2 += __shfl_xor(d2, s, 64);
            }
            float v1 = 0.5f*invx*inv_wx[y1]*d1 + 0.5f*inv_wz[y1]*wzw[(size_t)y1*Z_N + zb];
            unsigned long long p1 = pack_vi(v1, y1);
            bB = (p1 > bB) ? p1 : bB;
            if (h2) {
                float v2 = 0.5f*invx*inv_wx[y2]*d2 + 0.5f*inv_wz[y2]*wzw[(size_t)y2*Z_N + zb];
                unsigned long long p2 = pack_vi(v2, y2);
                bB = (p2 > bB) ? p2 : bB;
            }
        }
        if (lane == 0) red[wid] = bB;
    }
    __syncthreads();
    if (t == 0) {
        unsigned long long pm = sPM;
        unsigned enc = (unsigned)(pm >> 32);
        int idx = (int)(0xFFFFFFFFu - (unsigned)(pm & 0xFFFFFFFFull));
        int fin;
        if (sTakeA) {
            fin = idx;
        } else if (nB > 0) {
            unsigned long long pf = red[0];
            #pragma unroll
            for (int j = 1; j < 4; ++j) pf = (red[j] > pf) ? red[j] : pf;
            fin = (int)(0xFFFFFFFFu - (unsigned)(pf & 0xFFFFFFFFull));
        } else {
            fin = ctr[2];   // all-unact-nonpositive: ref argmax lands on first activated
        }
        final_idx[b] = fin;
        atomicAdd(&cnt[fin], 1);
        atomicMin(&segmin[fin], enc);
        atomicAdd(&zcnt[zb], 1);
    }
}

__global__ __launch_bounds__(256) void wx_out_kernel(
    const float* __restrict__ wxw, const float* __restrict__ inv_wx,
    const float* __restrict__ x, const float* __restrict__ inv_x,
    const int* __restrict__ final_idx, const int* __restrict__ cnt,
    const float* __restrict__ y_age, float* __restrict__ outw) {
    int j = blockIdx.x;
    int t = threadIdx.x;
    __shared__ int s_b[1024];
    __shared__ int s_n;
    if (t == 0) s_n = 0;
    __syncthreads();
    int c = cnt[j];
    if (c > 0) {
        for (int b = t; b < B_N; b += 256)
            if (final_idx[b] == j) { int p = atomicAdd(&s_n, 1); s_b[p] = b; }
    }
    __syncthreads();
    float inv = inv_wx[j];
    float lr = 1.0f / (y_age[j] + 1.0f);
    float fc = (float)c;
    float dv = (c > 0) ? fc : 1.0f;
    int n = s_n;
    float4 w = *reinterpret_cast<const float4*>(wxw + (size_t)j * X_N + t * 4);
    float4 wn = make_float4(w.x*inv, w.y*inv, w.z*inv, w.w*inv);
    if (c > 0) {
        float4 s = make_float4(0.f, 0.f, 0.f, 0.f);
        for (int m = 0; m < n; ++m) {
            int b = s_b[m];
            float ix = inv_x[b];
            float4 xv = *reinterpret_cast<const float4*>(x + (size_t)b * X_N + t * 4);
            s.x += xv.x * ix; s.y += xv.y * ix; s.z += xv.z * ix; s.w += xv.w * ix;
        }
        float f = lr / dv;
        wn.x += f * (s.x - fc * wn.x);
        wn.y += f * (s.y - fc * wn.y);
        wn.z += f * (s.z - fc * wn.z);
        wn.w += f * (s.w - fc * wn.w);
    }
    *reinterpret_cast<float4*>(outw + (size_t)j * X_N + t * 4) = wn;
}

__global__ __launch_bounds__(256) void wz_out_kernel(
    const float* __restrict__ wzw, const float* __restrict__ inv_wz,
    const int* __restrict__ zlab, const int* __restrict__ final_idx,
    const int* __restrict__ cnt, const float* __restrict__ y_age,
    float* __restrict__ outw) {
    int j = blockIdx.x;
    int t = threadIdx.x;
    __shared__ int s_c[1024];
    __shared__ int s_n;
    if (t == 0) s_n = 0;
    __syncthreads();
    int c = cnt[j];
    if (c > 0) {
        for (int b = t; b < B_N; b += 256)
            if (final_idx[b] == j) { int p = atomicAdd(&s_n, 1); s_c[p] = zlab[b]; }
    }
    __syncthreads();
    if (t >= 250) return;
    float inv = inv_wz[j];
    float lr = 1.0f / (y_age[j] + 1.0f);
    float fc = (float)c;
    float dv = (c > 0) ? fc : 1.0f;
    int n = s_n;
    float4 w = *reinterpret_cast<const float4*>(wzw + (size_t)j * Z_N + t * 4);
    float4 wn = make_float4(w.x*inv, w.y*inv, w.z*inv, w.w*inv);
    if (c > 0) {
        float4 s = make_float4(0.f, 0.f, 0.f, 0.f);
        for (int m = 0; m < n; ++m) {
            int d = s_c[m] - t * 4;
            if (d == 0) s.x += 1.f;
            else if (d == 1) s.y += 1.f;
            else if (d == 2) s.z += 1.f;
            else if (d == 3) s.w += 1.f;
        }
        float f = lr / dv;
        wn.x += f * (s.x - fc * wn.x);
        wn.y += f * (s.y - fc * wn.y);
        wn.z += f * (s.z - fc * wn.z);
        wn.w += f * (s.w - fc * wn.w);
    }
    *reinterpret_cast<float4*>(outw + (size_t)j * Z_N + t * 4) = wn;
}

// fused: row-norm of U + U update (row held in registers; one read, one write)
__global__ __launch_bounds__(256) void u_out_kernel(
    const float* __restrict__ uw, const int* __restrict__ zlab,
    const int* __restrict__ final_idx, const int* __restrict__ zcnt,
    const float* __restrict__ z_age, float* __restrict__ outw) {
    int cz = blockIdx.x;
    int t = threadIdx.x;
    const int lane = t & 63, wid = t >> 6;
    __shared__ int s_w[1024];
    __shared__ int s_n;
    __shared__ float rss[4];
    if (t == 0) s_n = 0;

    const float4* rowp4 = reinterpret_cast<const float4*>(uw + (size_t)cz * Y_N);
    float4 u[16];
    float ss = 0.f;
    #pragma unroll
    for (int p = 0; p < 16; ++p) {
        u[p] = rowp4[p * 256 + t];
        ss += u[p].x*u[p].x + u[p].y*u[p].y + u[p].z*u[p].z + u[p].w*u[p].w;
    }
    #pragma unroll
    for (int s = 32; s > 0; s >>= 1) ss += __shfl_xor(ss, s, 64);
    if (lane == 0) rss[wid] = ss;
    __syncthreads();
    float inv = 1.0f / fmaxf(sqrtf(rss[0] + rss[1] + rss[2] + rss[3]), 1e-12f);

    int c = zcnt[cz];
    if (c > 0) {
        for (int b = t; b < B_N; b += 256)
            if (zlab[b] == cz) { int p = atomicAdd(&s_n, 1); s_w[p] = final_idx[b]; }
    }
    __syncthreads();
    float zlr = 1.0f / (z_age[cz] + 1.0f);
    float fc = (float)c;
    float dv = (c > 0) ? fc : 1.0f;
    float f = zlr / dv;
    int n = s_n;
    float* outp = outw + (size_t)cz * Y_N;
    #pragma unroll
    for (int p = 0; p < 16; ++p) {
        int e4 = p * 256 + t;
        float4 un = make_float4(u[p].x*inv, u[p].y*inv, u[p].z*inv, u[p].w*inv);
        if (c > 0) {
            float4 s = make_float4(0.f, 0.f, 0.f, 0.f);
            for (int m = 0; m < n; ++m) {
                int d = s_w[m] - e4 * 4;
                if (d == 0) s.x += 1.f;
                else if (d == 1) s.y += 1.f;
                else if (d == 2) s.z += 1.f;
                else if (d == 3) s.w += 1.f;
            }
            un.x += f * (s.x - fc * un.x);
            un.y += f * (s.y - fc * un.y);
            un.z += f * (s.z - fc * un.z);
            un.w += f * (s.w - fc * un.w);
        }
        *reinterpret_cast<float4*>(outp + e4 * 4) = un;
    }
}

__global__ void thr_age_kernel(const int* __restrict__ cnt, const unsigned* __restrict__ segmin,
                               const float* __restrict__ y_age, const float* __restrict__ y_thr,
                               float* __restrict__ out_thr, float* __restrict__ out_age,
                               int* ctr) {
    int j = blockIdx.x * 256 + threadIdx.x;
    int c = cnt[j];
    float age = y_age[j];
    float thr = y_thr[j];
    float tn = thr;
    if (c > 0) {
        float lr = 1.0f / (age + 1.0f);
        float smin = dec_f(segmin[j]);
        float ycur = fminf(smin, 3.0f);
        if (ycur > 2.0f) ycur = 0.0f;
        tn = lr * ycur + (1.0f - lr) * thr;
    }
    out_thr[j] = tn;
    float an = age + (float)c;
    out_age[j] = an;
    unsigned long long m = __ballot(an >= 1.0f ? 1 : 0);
    if ((threadIdx.x & 63) == 0) atomicAdd(ctr + 1, (int)__popcll(m));
}

__global__ void zage_act_kernel(const int* __restrict__ zcnt, const float* __restrict__ z_age,
                                const int* __restrict__ ctr, float* __restrict__ out_zage,
                                float* __restrict__ out_act) {
    int i = blockIdx.x * 256 + threadIdx.x;
    if (i < Z_N) out_zage[i] = z_age[i] + (float)zcnt[i];
    if (i == 0) out_act[0] = (float)ctr[1];
}

extern "C" void kernel_launch(void* const* d_in, const int* in_sizes, int n_in,
                              void* d_out, int out_size, void* d_ws, size_t ws_size,
                              hipStream_t stream) {
    const float* x     = (const float*)d_in[0];
    const int*   z     = (const int*)d_in[1];
    const float* wxw   = (const float*)d_in[2];
    const float* wzw   = (const float*)d_in[3];
    const float* uw    = (const float*)d_in[4];
    const float* y_age = (const float*)d_in[5];
    const float* z_age = (const float*)d_in[6];
    const float* y_thr = (const float*)d_in[7];
    float* out = (float*)d_out;
    float* ws  = (float*)d_ws;
    char*  ob  = (char*)d_out;

    float* inv_x  = ws + WS_INV_X;
    float* inv_wx = ws + WS_INV_WX;
    float* inv_wz = ws + WS_INV_WZ;
    int* fidx = (int*)(ws + WS_FIDX);
    int* cnt  = (int*)(ws + WS_CNT);
    int* zcnt = (int*)(ws + WS_ZCNT);
    unsigned* segmin = (unsigned*)(ws + WS_SEGMIN);
    int* ctr = (int*)(ws + WS_CTR);
    unsigned long long* mbits = (unsigned long long*)(ws + WS_MBITS);
    int* ccnt = (int*)(ws + WS_CCNT);

    ushort_t* Bb = (ushort_t*)(ob + SCR_B_BYTES);
    ushort_t* Sc = (ushort_t*)(ob + SCR_S_BYTES);
    ushort_t* Ab = (ushort_t*)(ob + SCR_A_BYTES);
    unsigned* gcand = (unsigned*)(ob + SCR_CAND_BYTES);

    init_kernel<<<64, 256, 0, stream>>>(cnt, segmin, zcnt, ctr);
    rownorm_kernel<<<B_N, 256, 0, stream>>>(x, X_N, inv_x);
    unact_kernel<<<Y_N / 256, 256, 0, stream>>>(y_age, ctr, mbits);
    pack_x_kernel<<<(B_N * GK / 8) / 256, 256, 0, stream>>>(x, inv_x, z, Ab);
    pack_w_kernel<<<Y_N, 256, 0, stream>>>(wxw, wzw, Bb, inv_wx, inv_wz);
    mm128_kernel<<<(B_N / 128) * (Y_N / 128), 256, 0, stream>>>(Ab, Bb, Sc);
    scan_kernel<<<B_N, 256, 0, stream>>>(Sc, mbits, ctr, gcand, ccnt);
    rescore_kernel<<<B_N, 256, 0, stream>>>(gcand, ccnt, x, inv_x, wxw, inv_wx, wzw, inv_wz,
                                            z, y_thr, y_age, ctr, fidx, cnt, segmin, zcnt,
                                            out + OFF_MAXRESP);
    wx_out_kernel<<<Y_N, 256, 0, stream>>>(wxw, inv_wx, x, inv_x, fidx, cnt, y_age, out + OFF_WX);
    wz_out_kernel<<<Y_N, 256, 0, stream>>>(wzw, inv_wz, z, fidx, cnt, y_age, out + OFF_WZ);
    u_out_kernel<<<Z_N, 256, 0, stream>>>(uw, z, fidx, zcnt, z_age, out + OFF_U);
    thr_age_kernel<<<Y_N / 256, 256, 0, stream>>>(cnt, segmin, y_age, y_thr,
                                                  out + OFF_THR, out + OFF_AGE, ctr);
    zage_act_kernel<<<4, 256, 0, stream>>>(zcnt, z_age, ctr, out + OFF_ZAGE, out + OFF_ACT);
}

// Round 7
// 302.593 us; speedup vs baseline: 1.2833x; 1.2833x over previous
//
#include <hip/hip_runtime.h>

#define B_N 1024
#define X_N 1024
#define Y_N 16384
#define Z_N 1000
#define GK  2048
#define MARGIN 0.004f

// output float offsets
#define OFF_ACT      0
#define OFF_MAXRESP  1
#define OFF_WX       1025
#define OFF_WZ       16778241
#define OFF_U        33162241
#define OFF_THR      49546241
#define OFF_AGE      49562625
#define OFF_ZAGE     49579009

// scratch placed inside not-yet-written d_out regions (16B aligned byte offsets)
#define SCR_B_BYTES    4112ull       /* Bb f16 64MB region, in OFF_WX region */
#define SCR_S_BYTES    67112992ull   /* Sc f16 32MB, in OFF_WZ region */
#define SCR_A_BYTES    132648976ull  /* Ab f16 4MB,  in OFF_U region */
#define SCR_CAND_BYTES 136843296ull  /* u32[1024][512] = 2MB, in OFF_U region */

// ws float offsets
#define WS_INV_X    0
#define WS_INV_WX   1024
#define WS_INV_WZ   17408
#define WS_FIDX     38912   /* int[1024] */
#define WS_CNT      39936   /* int[16384] */
#define WS_ZCNT     56320   /* int[1024] */
#define WS_SEGMIN   57344   /* uint[16384] */
#define WS_CTR      73728   /* int[8]: [0]=unact_cnt [1]=act_cnt [2]=min_act_idx */
#define WS_MBITS    73736   /* u64[256] */
#define WS_CCNT     74248   /* int[1024] */

typedef unsigned short ushort_t;
typedef _Float16 f16x8 __attribute__((ext_vector_type(8)));
typedef float f32x4 __attribute__((ext_vector_type(4)));

__device__ __forceinline__ unsigned enc_f(float f) {
    unsigned u = __float_as_uint(f);
    return (u & 0x80000000u) ? ~u : (u | 0x80000000u);
}
__device__ __forceinline__ float dec_f(unsigned e) {
    unsigned u = (e & 0x80000000u) ? (e ^ 0x80000000u) : ~e;
    return __uint_as_float(u);
}
__device__ __forceinline__ unsigned long long pack_vi(float v, int y) {
    return ((unsigned long long)enc_f(v) << 32) |
           (unsigned long long)(0xFFFFFFFFu - (unsigned)y);
}
__device__ __forceinline__ ushort_t f2h(float f) {
    _Float16 h = (_Float16)f;           // RTNE
    ushort_t u; __builtin_memcpy(&u, &h, 2); return u;
}
__device__ __forceinline__ float h2f(unsigned lo16) {
    ushort_t u = (ushort_t)lo16; _Float16 h;
    __builtin_memcpy(&h, &u, 2); return (float)h;
}

#define GLOAD16(gp, lp) __builtin_amdgcn_global_load_lds( \
    (const __attribute__((address_space(1))) void*)(gp),  \
    (__attribute__((address_space(3))) void*)(lp), 16, 0, 0)

__global__ void init_kernel(int* cnt, unsigned* segmin, int* zcnt, int* ctr) {
    int i = blockIdx.x * 256 + threadIdx.x;
    if (i < Y_N) { cnt[i] = 0; segmin[i] = 0xFFFFFFFFu; }
    if (i < 1024) zcnt[i] = 0;
    if (i < 8) ctr[i] = (i == 2) ? 0x7FFFFFFF : 0;
}

__global__ void rownorm_kernel(const float* __restrict__ src, int rowlen,
                               float* __restrict__ inv_out) {
    int row = blockIdx.x;
    const float* p = src + (size_t)row * rowlen;
    float ss = 0.f;
    for (int e = threadIdx.x; e < rowlen; e += 256) { float v = p[e]; ss += v * v; }
    #pragma unroll
    for (int s = 32; s > 0; s >>= 1) ss += __shfl_xor(ss, s, 64);
    __shared__ float red[4];
    if ((threadIdx.x & 63) == 0) red[threadIdx.x >> 6] = ss;
    __syncthreads();
    if (threadIdx.x == 0) {
        float tot = red[0] + red[1] + red[2] + red[3];
        inv_out[row] = 1.0f / fmaxf(sqrtf(tot), 1e-12f);
    }
}

__global__ void unact_kernel(const float* __restrict__ y_age, int* ctr,
                             unsigned long long* __restrict__ mbits) {
    int i = blockIdx.x * 256 + threadIdx.x;
    int a = (y_age[i] < 1.0f) ? 1 : 0;
    unsigned long long m = __ballot(a);
    int mi = a ? 0x7FFFFFFF : i;   // min index over ACTIVATED neurons
    #pragma unroll
    for (int s = 32; s > 0; s >>= 1) mi = min(mi, __shfl_xor(mi, s, 64));
    if ((threadIdx.x & 63) == 0) {
        atomicAdd(ctr, (int)__popcll(m));
        mbits[i >> 6] = m;
        if (mi != 0x7FFFFFFF) atomicMin(&ctr[2], mi);
    }
}

// A [B_N][GK] f16: cols 0..1023 = 0.5*x_hat ; cols 1024.. = 0.5*one_hot(z)
__global__ void pack_x_kernel(const float* __restrict__ x, const float* __restrict__ inv_x,
                              const int* __restrict__ zlab, ushort_t* __restrict__ A) {
    int i = blockIdx.x * 256 + threadIdx.x;
    int idx = i * 8;
    int bb = idx >> 11;
    int k = idx & (GK - 1);
    ushort_t o[8];
    if (k < X_N) {
        float invx = 0.5f * inv_x[bb];
        const float* xr = x + (size_t)bb * X_N + k;
        #pragma unroll
        for (int j = 0; j < 8; ++j) o[j] = f2h(invx * xr[j]);
    } else {
        int zb = zlab[bb];
        #pragma unroll
        for (int j = 0; j < 8; ++j) o[j] = ((k + j - X_N) == zb) ? (ushort_t)0x3800 : (ushort_t)0;
    }
    *reinterpret_cast<uint4*>(A + idx) = *reinterpret_cast<uint4*>(o);
}

// fused: row-norms of wxw/wzw + pack B row [Y_N][GK] f16 (one block per y)
__global__ __launch_bounds__(256) void pack_w_kernel(
    const float* __restrict__ wxw, const float* __restrict__ wzw,
    ushort_t* __restrict__ Bm, float* __restrict__ inv_wx, float* __restrict__ inv_wz) {
    const int y = blockIdx.x, t = threadIdx.x;
    const int lane = t & 63, wid = t >> 6;
    float4 a = reinterpret_cast<const float4*>(wxw + (size_t)y * X_N)[t];
    float4 zv = make_float4(0.f, 0.f, 0.f, 0.f);
    if (t < 250) zv = reinterpret_cast<const float4*>(wzw + (size_t)y * Z_N)[t];
    float s1 = a.x*a.x + a.y*a.y + a.z*a.z + a.w*a.w;
    float s2 = zv.x*zv.x + zv.y*zv.y + zv.z*zv.z + zv.w*zv.w;
    #pragma unroll
    for (int s = 32; s > 0; s >>= 1) {
        s1 += __shfl_xor(s1, s, 64);
        s2 += __shfl_xor(s2, s, 64);
    }
    __shared__ float r1[4], r2[4];
    if (lane == 0) { r1[wid] = s1; r2[wid] = s2; }
    __syncthreads();
    float inv1 = 1.0f / fmaxf(sqrtf(r1[0] + r1[1] + r1[2] + r1[3]), 1e-12f);
    float inv2 = 1.0f / fmaxf(sqrtf(r2[0] + r2[1] + r2[2] + r2[3]), 1e-12f);
    ushort_t o1[4] = { f2h(a.x*inv1), f2h(a.y*inv1), f2h(a.z*inv1), f2h(a.w*inv1) };
    *reinterpret_cast<uint2*>(Bm + (size_t)y * GK + t * 4) = *reinterpret_cast<uint2*>(o1);
    ushort_t o2[4] = { 0, 0, 0, 0 };
    if (t < 250) { o2[0]=f2h(zv.x*inv2); o2[1]=f2h(zv.y*inv2); o2[2]=f2h(zv.z*inv2); o2[3]=f2h(zv.w*inv2); }
    *reinterpret_cast<uint2*>(Bm + (size_t)y * GK + X_N + t * 4) = *reinterpret_cast<uint2*>(o2);
    if (t == 0) { inv_wx[y] = inv1; inv_wz[y] = inv2; }
}

// f16 MFMA GEMM, 256x256 tile, BK=64, 8 waves (2Mx4N), counted-vmcnt dbuf:
// loads for tile k+1 stay in flight across the barrier (no drain-to-0 in loop).
__global__ __launch_bounds__(512, 1) void mm256_kernel(const ushort_t* __restrict__ A,
                                                       const ushort_t* __restrict__ Bm,
                                                       ushort_t* __restrict__ S) {
    // [buf][mat][slot = g*256 + row][8 f16]; g in [0,8) covers BK=64
    __shared__ __align__(16) _Float16 lds[2][2][2048][8];
    const int t = threadIdx.x;
    const int wid = t >> 6, lane = t & 63;
    const int bid = blockIdx.x;
    const int lb = (bid & 7) * 32 + (bid >> 3);   // bijective: 256 % 8 == 0
    const int mt = lb & 3, nt = lb >> 2;
    const int b0 = mt * 256, y0 = nt * 256;
    const int wr = wid >> 2, wc = wid & 3;        // 2 x 4 waves
    const int r = lane & 15, gq = lane >> 4;
    const int NK = GK / 64;                        // 32 K-tiles

    f32x4 acc[8][4];
    #pragma unroll
    for (int i = 0; i < 8; ++i)
        #pragma unroll
        for (int j = 0; j < 4; ++j) acc[i][j] = (f32x4){0.f, 0.f, 0.f, 0.f};

    // 8 gload_lds per thread per stage (4 A + 4 B, interleaved issue order)
    auto stage = [&](int buf, int k0) {
        #pragma unroll
        for (int rr = 0; rr < 4; ++rr) {
            int s = rr * 512 + t;
            int row = s & 255, g = s >> 8;
            GLOAD16(A  + (size_t)(b0 + row) * GK + k0 + g * 8, &lds[buf][0][s][0]);
            GLOAD16(Bm + (size_t)(y0 + row) * GK + k0 + g * 8, &lds[buf][1][s][0]);
        }
    };

    // prologue: 2-deep prefetch; wait only for tile 0 (8 newer stay in flight)
    stage(0, 0);
    stage(1, 64);
    asm volatile("s_waitcnt vmcnt(8)" ::: "memory");
    __builtin_amdgcn_s_barrier();
    asm volatile("" ::: "memory");

    int cur = 0;
    for (int ks = 0; ks < NK; ++ks) {
        // compute from buf[cur] (tile ks); buf[cur^1] holds tile ks+1 (in flight or landed)
        #pragma unroll
        for (int ksub = 0; ksub < 2; ++ksub) {
            const int g = ksub * 4 + gq;
            f16x8 bF[4];
            #pragma unroll
            for (int nf = 0; nf < 4; ++nf)
                bF[nf] = *reinterpret_cast<const f16x8*>(
                    &lds[cur][1][g * 256 + wc * 64 + nf * 16 + r][0]);
            __builtin_amdgcn_s_setprio(1);
            #pragma unroll
            for (int mf = 0; mf < 8; ++mf) {
                f16x8 aF = *reinterpret_cast<const f16x8*>(
                    &lds[cur][0][g * 256 + wr * 128 + mf * 16 + r][0]);
                #pragma unroll
                for (int nf = 0; nf < 4; ++nf)
                    acc[mf][nf] = __builtin_amdgcn_mfma_f32_16x16x32_f16(
                        aF, bF[nf], acc[mf][nf], 0, 0, 0);
            }
            __builtin_amdgcn_s_setprio(0);
        }
        if (ks == NK - 1) break;

        __builtin_amdgcn_s_barrier();            // all waves done reading buf[cur]
        asm volatile("" ::: "memory");
        if (ks + 2 < NK) {
            stage(cur, (ks + 2) * 64);           // overwrite the buffer just consumed
            asm volatile("s_waitcnt vmcnt(8)" ::: "memory");  // tile ks+1 fully landed
        } else {
            asm volatile("s_waitcnt vmcnt(0)" ::: "memory");  // pipeline tail
        }
        __builtin_amdgcn_s_barrier();            // all waves' tile-(ks+1) loads landed
        asm volatile("" ::: "memory");
        cur ^= 1;
    }

    // C layout: col = lane&15, row = (lane>>4)*4 + reg
    #pragma unroll
    for (int mf = 0; mf < 8; ++mf) {
        int bg = b0 + wr * 128 + mf * 16 + gq * 4;
        #pragma unroll
        for (int nf = 0; nf < 4; ++nf) {
            int yg = y0 + wc * 64 + nf * 16 + r;
            f32x4 c = acc[mf][nf];
            #pragma unroll
            for (int q = 0; q < 4; ++q)
                S[(size_t)(bg + q) * Y_N + yg] = f2h(c[q]);
        }
    }
}

// per-row: approx max + candidate collection (per-row slab, LDS atomics only)
__global__ __launch_bounds__(256) void scan_kernel(
    const ushort_t* __restrict__ scores, const unsigned long long* __restrict__ mbits,
    const int* __restrict__ ctr, unsigned* __restrict__ gcand, int* __restrict__ ccnt) {
    const int b = blockIdx.x, t = threadIdx.x;
    const int lane = t & 63, wid = t >> 6;
    const uint4* srow = reinterpret_cast<const uint4*>(scores + (size_t)b * Y_N);

    float vmax = -1e30f, mmax = -1e30f;
    for (int c = t; c < Y_N / 8; c += 256) {
        uint4 pk = srow[c];
        int yb = c * 8;
        unsigned m8 = (unsigned)((mbits[yb >> 6] >> (yb & 63)) & 0xFFull);
        unsigned w[4] = {pk.x, pk.y, pk.z, pk.w};
        #pragma unroll
        for (int j = 0; j < 4; ++j) {
            float v0 = h2f(w[j] & 0xFFFFu);
            float v1 = h2f(w[j] >> 16);
            vmax = fmaxf(vmax, fmaxf(v0, v1));
            mmax = fmaxf(mmax, v0 * (float)((m8 >> (2 * j)) & 1u));
            mmax = fmaxf(mmax, v1 * (float)((m8 >> (2 * j + 1)) & 1u));
        }
    }
    #pragma unroll
    for (int s = 32; s > 0; s >>= 1) {
        vmax = fmaxf(vmax, __shfl_xor(vmax, s, 64));
        mmax = fmaxf(mmax, __shfl_xor(mmax, s, 64));
    }
    __shared__ float rv[4], rm[4];
    __shared__ int nA_s, nB_s;
    __shared__ int cA[256], cB[256];
    if (lane == 0) { rv[wid] = vmax; rm[wid] = mmax; }
    if (t == 0) { nA_s = 0; nB_s = 0; }
    __syncthreads();
    float tA = fmaxf(fmaxf(rv[0], rv[1]), fmaxf(rv[2], rv[3])) - MARGIN;
    float tB = fmaxf(fmaxf(rm[0], rm[1]), fmaxf(rm[2], rm[3])) - MARGIN;
    bool anyu = ctr[0] > 0;

    for (int c = t; c < Y_N / 8; c += 256) {
        uint4 pk = srow[c];
        int yb = c * 8;
        unsigned m8 = (unsigned)((mbits[yb >> 6] >> (yb & 63)) & 0xFFull);
        unsigned w[4] = {pk.x, pk.y, pk.z, pk.w};
        #pragma unroll
        for (int j = 0; j < 8; ++j) {
            float v = h2f((j & 1) ? (w[j >> 1] >> 16) : (w[j >> 1] & 0xFFFFu));
            if (v >= tA) { int p = atomicAdd(&nA_s, 1); if (p < 256) cA[p] = yb + j; }
            if (anyu && ((m8 >> j) & 1u) && v >= tB) {
                int p = atomicAdd(&nB_s, 1); if (p < 256) cB[p] = yb + j;
            }
        }
    }
    __syncthreads();
    int nA = min(nA_s, 256), nB = min(nB_s, 256);
    unsigned* slab = gcand + (size_t)b * 512;
    for (int i = t; i < nA; i += 256) slab[i] = (unsigned)cA[i];
    for (int i = t; i < nB; i += 256) slab[256 + i] = (unsigned)cB[i];
    if (t == 0) ccnt[b] = nA | (nB << 16);
}

// per-row: exact fp32 rescore (A list, judge, conditional B list) + finalize
__global__ __launch_bounds__(256) void rescore_kernel(
    const unsigned* __restrict__ gcand, const int* __restrict__ ccnt,
    const float* __restrict__ x, const float* __restrict__ inv_x,
    const float* __restrict__ wxw, const float* __restrict__ inv_wx,
    const float* __restrict__ wzw, const float* __restrict__ inv_wz,
    const int* __restrict__ zlab, const float* __restrict__ y_thr,
    const float* __restrict__ y_age, const int* __restrict__ ctr,
    int* final_idx, int* cnt, unsigned* segmin, int* zcnt,
    float* __restrict__ out_maxresp) {
    const int b = blockIdx.x, t = threadIdx.x;
    const int lane = t & 63, wid = t >> 6;
    int pc = ccnt[b];
    int nA = pc & 0xFFFF, nB = pc >> 16;
    int zb = zlab[b];
    float invx = inv_x[b];
    const unsigned* slab = gcand + (size_t)b * 512;

    const float4* xr = reinterpret_cast<const float4*>(x + (size_t)b * X_N);
    float4 xv[4];
    #pragma unroll
    for (int j = 0; j < 4; ++j) xv[j] = xr[j * 64 + lane];

    __shared__ unsigned long long red[4];
    __shared__ unsigned long long sPM;
    __shared__ int sTakeA;

    // ---- list A ----
    unsigned long long bA = 0ull;
    for (int c = wid; c < nA; c += 8) {
        int y1 = (int)slab[c];
        int c2 = c + 4;
        bool h2 = c2 < nA;
        int y2 = (int)slab[h2 ? c2 : c];
        const float4* w1 = reinterpret_cast<const float4*>(wxw + (size_t)y1 * X_N);
        const float4* w2 = reinterpret_cast<const float4*>(wxw + (size_t)y2 * X_N);
        float d1 = 0.f, d2 = 0.f;
        #pragma unroll
        for (int j = 0; j < 4; ++j) {
            float4 a1 = w1[j * 64 + lane];
            float4 a2 = w2[j * 64 + lane];
            d1 += xv[j].x*a1.x + xv[j].y*a1.y + xv[j].z*a1.z + xv[j].w*a1.w;
            d2 += xv[j].x*a2.x + xv[j].y*a2.y + xv[j].z*a2.z + xv[j].w*a2.w;
        }
        #pragma unroll
        for (int s = 32; s > 0; s >>= 1) {
            d1 += __shfl_xor(d1, s, 64);
            d2 += __shfl_xor(d2, s, 64);
        }
        float v1 = 0.5f*invx*inv_wx[y1]*d1 + 0.5f*inv_wz[y1]*wzw[(size_t)y1*Z_N + zb];
        unsigned long long p1 = pack_vi(v1, y1);
        bA = (p1 > bA) ? p1 : bA;
        if (h2) {
            float v2 = 0.5f*invx*inv_wx[y2]*d2 + 0.5f*inv_wz[y2]*wzw[(size_t)y2*Z_N + zb];
            unsigned long long p2 = pack_vi(v2, y2);
            bA = (p2 > bA) ? p2 : bA;
        }
    }
    if (lane == 0) red[wid] = bA;
    __syncthreads();
    if (t == 0) {
        unsigned long long pm = red[0];
        #pragma unroll
        for (int j = 1; j < 4; ++j) pm = (red[j] > pm) ? red[j] : pm;
        sPM = pm;
        unsigned enc = (unsigned)(pm >> 32);
        int idx = (int)(0xFFFFFFFFu - (unsigned)(pm & 0xFFFFFFFFull));
        float mresp = dec_f(enc);
        out_maxresp[b] = mresp;
        bool judge = (mresp > y_thr[idx]) || (y_age[idx] < 1.0f);
        bool anyu = ctr[0] > 0;
        sTakeA = (judge || !anyu) ? 1 : 0;
    }
    __syncthreads();

    // ---- list B only when fallback needed ----
    if (!sTakeA) {
        unsigned long long bB = 0ull;
        for (int c = wid; c < nB; c += 8) {
            int y1 = (int)slab[256 + c];
            int c2 = c + 4;
            bool h2 = c2 < nB;
            int y2 = (int)slab[256 + (h2 ? c2 : c)];
            const float4* w1 = reinterpret_cast<const float4*>(wxw + (size_t)y1 * X_N);
            const float4* w2 = reinterpret_cast<const float4*>(wxw + (size_t)y2 * X_N);
            float d1 = 0.f, d2 = 0.f;
            #pragma unroll
            for (int j = 0; j < 4; ++j) {
                float4 a1 = w1[j * 64 + lane];
                float4 a2 = w2[j * 64 + lane];
                d1 += xv[j].x*a1.x + xv[j].y*a1.y + xv[j].z*a1.z + xv[j].w*a1.w;
                d2 += xv[j].x*a2.x + xv[j].y*a2.y + xv[j].z*a2.z + xv[j].w*a2.w;
            }
            #pragma unroll
            for (int s = 32; s > 0; s >>= 1) {
                d1 += __shfl_xor(d1, s, 64);
                d2 += __shfl_xor(d2, s, 64);
            }
            float v1 = 0.5f*invx*inv_wx[y1]*d1 + 0.5f*inv_wz[y1]*wzw[(size_t)y1*Z_N + zb];
            unsigned long long p1 = pack_vi(v1, y1);
            bB = (p1 > bB) ? p1 : bB;
            if (h2) {
                float v2 = 0.5f*invx*inv_wx[y2]*d2 + 0.5f*inv_wz[y2]*wzw[(size_t)y2*Z_N + zb];
                unsigned long long p2 = pack_vi(v2, y2);
                bB = (p2 > bB) ? p2 : bB;
            }
        }
        if (lane == 0) red[wid] = bB;
    }
    __syncthreads();
    if (t == 0) {
        unsigned long long pm = sPM;
        unsigned enc = (unsigned)(pm >> 32);
        int idx = (int)(0xFFFFFFFFu - (unsigned)(pm & 0xFFFFFFFFull));
        int fin;
        if (sTakeA) {
            fin = idx;
        } else if (nB > 0) {
            unsigned long long pf = red[0];
            #pragma unroll
            for (int j = 1; j < 4; ++j) pf = (red[j] > pf) ? red[j] : pf;
            fin = (int)(0xFFFFFFFFu - (unsigned)(pf & 0xFFFFFFFFull));
        } else {
            fin = ctr[2];   // all-unact-nonpositive: ref argmax lands on first activated
        }
        final_idx[b] = fin;
        atomicAdd(&cnt[fin], 1);
        atomicMin(&segmin[fin], enc);
        atomicAdd(&zcnt[zb], 1);
    }
}

__global__ __launch_bounds__(256) void wx_out_kernel(
    const float* __restrict__ wxw, const float* __restrict__ inv_wx,
    const float* __restrict__ x, const float* __restrict__ inv_x,
    const int* __restrict__ final_idx, const int* __restrict__ cnt,
    const float* __restrict__ y_age, float* __restrict__ outw) {
    int j = blockIdx.x;
    int t = threadIdx.x;
    __shared__ int s_b[1024];
    __shared__ int s_n;
    if (t == 0) s_n = 0;
    __syncthreads();
    int c = cnt[j];
    if (c > 0) {
        for (int b = t; b < B_N; b += 256)
            if (final_idx[b] == j) { int p = atomicAdd(&s_n, 1); s_b[p] = b; }
    }
    __syncthreads();
    float inv = inv_wx[j];
    float lr = 1.0f / (y_age[j] + 1.0f);
    float fc = (float)c;
    float dv = (c > 0) ? fc : 1.0f;
    int n = s_n;
    float4 w = *reinterpret_cast<const float4*>(wxw + (size_t)j * X_N + t * 4);
    float4 wn = make_float4(w.x*inv, w.y*inv, w.z*inv, w.w*inv);
    if (c > 0) {
        float4 s = make_float4(0.f, 0.f, 0.f, 0.f);
        for (int m = 0; m < n; ++m) {
            int b = s_b[m];
            float ix = inv_x[b];
            float4 xv = *reinterpret_cast<const float4*>(x + (size_t)b * X_N + t * 4);
            s.x += xv.x * ix; s.y += xv.y * ix; s.z += xv.z * ix; s.w += xv.w * ix;
        }
        float f = lr / dv;
        wn.x += f * (s.x - fc * wn.x);
        wn.y += f * (s.y - fc * wn.y);
        wn.z += f * (s.z - fc * wn.z);
        wn.w += f * (s.w - fc * wn.w);
    }
    *reinterpret_cast<float4*>(outw + (size_t)j * X_N + t * 4) = wn;
}

__global__ __launch_bounds__(256) void wz_out_kernel(
    const float* __restrict__ wzw, const float* __restrict__ inv_wz,
    const int* __restrict__ zlab, const int* __restrict__ final_idx,
    const int* __restrict__ cnt, const float* __restrict__ y_age,
    float* __restrict__ outw) {
    int j = blockIdx.x;
    int t = threadIdx.x;
    __shared__ int s_c[1024];
    __shared__ int s_n;
    if (t == 0) s_n = 0;
    __syncthreads();
    int c = cnt[j];
    if (c > 0) {
        for (int b = t; b < B_N; b += 256)
            if (final_idx[b] == j) { int p = atomicAdd(&s_n, 1); s_c[p] = zlab[b]; }
    }
    __syncthreads();
    if (t >= 250) return;
    float inv = inv_wz[j];
    float lr = 1.0f / (y_age[j] + 1.0f);
    float fc = (float)c;
    float dv = (c > 0) ? fc : 1.0f;
    int n = s_n;
    float4 w = *reinterpret_cast<const float4*>(wzw + (size_t)j * Z_N + t * 4);
    float4 wn = make_float4(w.x*inv, w.y*inv, w.z*inv, w.w*inv);
    if (c > 0) {
        float4 s = make_float4(0.f, 0.f, 0.f, 0.f);
        for (int m = 0; m < n; ++m) {
            int d = s_c[m] - t * 4;
            if (d == 0) s.x += 1.f;
            else if (d == 1) s.y += 1.f;
            else if (d == 2) s.z += 1.f;
            else if (d == 3) s.w += 1.f;
        }
        float f = lr / dv;
        wn.x += f * (s.x - fc * wn.x);
        wn.y += f * (s.y - fc * wn.y);
        wn.z += f * (s.z - fc * wn.z);
        wn.w += f * (s.w - fc * wn.w);
    }
    *reinterpret_cast<float4*>(outw + (size_t)j * Z_N + t * 4) = wn;
}

// fused: row-norm of U + U update (row held in registers; one read, one write)
__global__ __launch_bounds__(256) void u_out_kernel(
    const float* __restrict__ uw, const int* __restrict__ zlab,
    const int* __restrict__ final_idx, const int* __restrict__ zcnt,
    const float* __restrict__ z_age, float* __restrict__ outw) {
    int cz = blockIdx.x;
    int t = threadIdx.x;
    const int lane = t & 63, wid = t >> 6;
    __shared__ int s_w[1024];
    __shared__ int s_n;
    __shared__ float rss[4];
    if (t == 0) s_n = 0;

    const float4* rowp4 = reinterpret_cast<const float4*>(uw + (size_t)cz * Y_N);
    float4 u[16];
    float ss = 0.f;
    #pragma unroll
    for (int p = 0; p < 16; ++p) {
        u[p] = rowp4[p * 256 + t];
        ss += u[p].x*u[p].x + u[p].y*u[p].y + u[p].z*u[p].z + u[p].w*u[p].w;
    }
    #pragma unroll
    for (int s = 32; s > 0; s >>= 1) ss += __shfl_xor(ss, s, 64);
    if (lane == 0) rss[wid] = ss;
    __syncthreads();
    float inv = 1.0f / fmaxf(sqrtf(rss[0] + rss[1] + rss[2] + rss[3]), 1e-12f);

    int c = zcnt[cz];
    if (c > 0) {
        for (int b = t; b < B_N; b += 256)
            if (zlab[b] == cz) { int p = atomicAdd(&s_n, 1); s_w[p] = final_idx[b]; }
    }
    __syncthreads();
    float zlr = 1.0f / (z_age[cz] + 1.0f);
    float fc = (float)c;
    float dv = (c > 0) ? fc : 1.0f;
    float f = zlr / dv;
    int n = s_n;
    float* outp = outw + (size_t)cz * Y_N;
    #pragma unroll
    for (int p = 0; p < 16; ++p) {
        int e4 = p * 256 + t;
        float4 un = make_float4(u[p].x*inv, u[p].y*inv, u[p].z*inv, u[p].w*inv);
        if (c > 0) {
            float4 s = make_float4(0.f, 0.f, 0.f, 0.f);
            for (int m = 0; m < n; ++m) {
                int d = s_w[m] - e4 * 4;
                if (d == 0) s.x += 1.f;
                else if (d == 1) s.y += 1.f;
                else if (d == 2) s.z += 1.f;
                else if (d == 3) s.w += 1.f;
            }
            un.x += f * (s.x - fc * un.x);
            un.y += f * (s.y - fc * un.y);
            un.z += f * (s.z - fc * un.z);
            un.w += f * (s.w - fc * un.w);
        }
        *reinterpret_cast<float4*>(outp + e4 * 4) = un;
    }
}

__global__ void thr_age_kernel(const int* __restrict__ cnt, const unsigned* __restrict__ segmin,
                               const float* __restrict__ y_age, const float* __restrict__ y_thr,
                               float* __restrict__ out_thr, float* __restrict__ out_age,
                               int* ctr) {
    int j = blockIdx.x * 256 + threadIdx.x;
    int c = cnt[j];
    float age = y_age[j];
    float thr = y_thr[j];
    float tn = thr;
    if (c > 0) {
        float lr = 1.0f / (age + 1.0f);
        float smin = dec_f(segmin[j]);
        float ycur = fminf(smin, 3.0f);
        if (ycur > 2.0f) ycur = 0.0f;
        tn = lr * ycur + (1.0f - lr) * thr;
    }
    out_thr[j] = tn;
    float an = age + (float)c;
    out_age[j] = an;
    unsigned long long m = __ballot(an >= 1.0f ? 1 : 0);
    if ((threadIdx.x & 63) == 0) atomicAdd(ctr + 1, (int)__popcll(m));
}

__global__ void zage_act_kernel(const int* __restrict__ zcnt, const float* __restrict__ z_age,
                                const int* __restrict__ ctr, float* __restrict__ out_zage,
                                float* __restrict__ out_act) {
    int i = blockIdx.x * 256 + threadIdx.x;
    if (i < Z_N) out_zage[i] = z_age[i] + (float)zcnt[i];
    if (i == 0) out_act[0] = (float)ctr[1];
}

extern "C" void kernel_launch(void* const* d_in, const int* in_sizes, int n_in,
                              void* d_out, int out_size, void* d_ws, size_t ws_size,
                              hipStream_t stream) {
    const float* x     = (const float*)d_in[0];
    const int*   z     = (const int*)d_in[1];
    const float* wxw   = (const float*)d_in[2];
    const float* wzw   = (const float*)d_in[3];
    const float* uw    = (const float*)d_in[4];
    const float* y_age = (const float*)d_in[5];
    const float* z_age = (const float*)d_in[6];
    const float* y_thr = (const float*)d_in[7];
    float* out = (float*)d_out;
    float* ws  = (float*)d_ws;
    char*  ob  = (char*)d_out;

    float* inv_x  = ws + WS_INV_X;
    float* inv_wx = ws + WS_INV_WX;
    float* inv_wz = ws + WS_INV_WZ;
    int* fidx = (int*)(ws + WS_FIDX);
    int* cnt  = (int*)(ws + WS_CNT);
    int* zcnt = (int*)(ws + WS_ZCNT);
    unsigned* segmin = (unsigned*)(ws + WS_SEGMIN);
    int* ctr = (int*)(ws + WS_CTR);
    unsigned long long* mbits = (unsigned long long*)(ws + WS_MBITS);
    int* ccnt = (int*)(ws + WS_CCNT);

    ushort_t* Bb = (ushort_t*)(ob + SCR_B_BYTES);
    ushort_t* Sc = (ushort_t*)(ob + SCR_S_BYTES);
    ushort_t* Ab = (ushort_t*)(ob + SCR_A_BYTES);
    unsigned* gcand = (unsigned*)(ob + SCR_CAND_BYTES);

    init_kernel<<<64, 256, 0, stream>>>(cnt, segmin, zcnt, ctr);
    rownorm_kernel<<<B_N, 256, 0, stream>>>(x, X_N, inv_x);
    unact_kernel<<<Y_N / 256, 256, 0, stream>>>(y_age, ctr, mbits);
    pack_x_kernel<<<(B_N * GK / 8) / 256, 256, 0, stream>>>(x, inv_x, z, Ab);
    pack_w_kernel<<<Y_N, 256, 0, stream>>>(wxw, wzw, Bb, inv_wx, inv_wz);
    mm256_kernel<<<(B_N / 256) * (Y_N / 256), 512, 0, stream>>>(Ab, Bb, Sc);
    scan_kernel<<<B_N, 256, 0, stream>>>(Sc, mbits, ctr, gcand, ccnt);
    rescore_kernel<<<B_N, 256, 0, stream>>>(gcand, ccnt, x, inv_x, wxw, inv_wx, wzw, inv_wz,
                                            z, y_thr, y_age, ctr, fidx, cnt, segmin, zcnt,
                                            out + OFF_MAXRESP);
    wx_out_kernel<<<Y_N, 256, 0, stream>>>(wxw, inv_wx, x, inv_x, fidx, cnt, y_age, out + OFF_WX);
    wz_out_kernel<<<Y_N, 256, 0, stream>>>(wzw, inv_wz, z, fidx, cnt, y_age, out + OFF_WZ);
    u_out_kernel<<<Z_N, 256, 0, stream>>>(uw, z, fidx, zcnt, z_age, out + OFF_U);
    thr_age_kernel<<<Y_N / 256, 256, 0, stream>>>(cnt, segmin, y_age, y_thr,
                                                  out + OFF_THR, out + OFF_AGE, ctr);
    zage_act_kernel<<<4, 256, 0, stream>>>(zcnt, z_age, ctr, out + OFF_ZAGE, out + OFF_ACT);
}

// Round 8
// 289.718 us; speedup vs baseline: 1.3404x; 1.0444x over previous
//
#include <hip/hip_runtime.h>

#define B_N 1024
#define X_N 1024
#define Y_N 16384
#define Z_N 1000
#define GK  2048
#define MARGIN 0.004f

// output float offsets
#define OFF_ACT      0
#define OFF_MAXRESP  1
#define OFF_WX       1025
#define OFF_WZ       16778241
#define OFF_U        33162241
#define OFF_THR      49546241
#define OFF_AGE      49562625
#define OFF_ZAGE     49579009

// scratch placed inside not-yet-written d_out regions (16B aligned byte offsets)
#define SCR_B_BYTES    4112ull       /* Bb f16 64MB, in OFF_WX region */
#define SCR_S_BYTES    67112992ull   /* Sc f16 32MB, in OFF_WZ region */
#define SCR_A_BYTES    132648976ull  /* Ab f16 4MB,  in OFF_U region */
#define SCR_CAND_BYTES 136843296ull  /* u32[1024][512] = 2MB, in OFF_U region */

// ws float offsets
#define WS_INV_X    0
#define WS_INV_WX   1024
#define WS_INV_WZ   17408
#define WS_FIDX     38912   /* int[1024] */
#define WS_CNT      39936   /* int[16384] */
#define WS_ZCNT     56320   /* int[1024] */
#define WS_SEGMIN   57344   /* uint[16384] */
#define WS_CTR      73728   /* int[8]: [0]=unact_cnt [1]=act_cnt [2]=min_act_idx */
#define WS_MBITS    73736   /* u64[256] */
#define WS_CCNT     74248   /* int[1024] */

typedef unsigned short ushort_t;
typedef _Float16 f16x8 __attribute__((ext_vector_type(8)));
typedef float f32x4 __attribute__((ext_vector_type(4)));

__device__ __forceinline__ unsigned enc_f(float f) {
    unsigned u = __float_as_uint(f);
    return (u & 0x80000000u) ? ~u : (u | 0x80000000u);
}
__device__ __forceinline__ float dec_f(unsigned e) {
    unsigned u = (e & 0x80000000u) ? (e ^ 0x80000000u) : ~e;
    return __uint_as_float(u);
}
__device__ __forceinline__ unsigned long long pack_vi(float v, int y) {
    return ((unsigned long long)enc_f(v) << 32) |
           (unsigned long long)(0xFFFFFFFFu - (unsigned)y);
}
__device__ __forceinline__ ushort_t f2h(float f) {
    _Float16 h = (_Float16)f;           // RTNE
    ushort_t u; __builtin_memcpy(&u, &h, 2); return u;
}
__device__ __forceinline__ float h2f(unsigned lo16) {
    ushort_t u = (ushort_t)lo16; _Float16 h;
    __builtin_memcpy(&h, &u, 2); return (float)h;
}

#define GLOAD16(gp, lp) __builtin_amdgcn_global_load_lds( \
    (const __attribute__((address_space(1))) void*)(gp),  \
    (__attribute__((address_space(3))) void*)(lp), 16, 0, 0)

__global__ void init_kernel(int* cnt, unsigned* segmin, int* zcnt, int* ctr) {
    int i = blockIdx.x * 256 + threadIdx.x;
    if (i < Y_N) { cnt[i] = 0; segmin[i] = 0xFFFFFFFFu; }
    if (i < 1024) zcnt[i] = 0;
    if (i < 8) ctr[i] = (i == 2) ? 0x7FFFFFFF : 0;
}

__global__ void unact_kernel(const float* __restrict__ y_age, int* ctr,
                             unsigned long long* __restrict__ mbits) {
    int i = blockIdx.x * 256 + threadIdx.x;
    int a = (y_age[i] < 1.0f) ? 1 : 0;
    unsigned long long m = __ballot(a);
    int mi = a ? 0x7FFFFFFF : i;   // min index over ACTIVATED neurons
    #pragma unroll
    for (int s = 32; s > 0; s >>= 1) mi = min(mi, __shfl_xor(mi, s, 64));
    if ((threadIdx.x & 63) == 0) {
        atomicAdd(ctr, (int)__popcll(m));
        mbits[i >> 6] = m;
        if (mi != 0x7FFFFFFF) atomicMin(&ctr[2], mi);
    }
}

// fused: row-norm of x + pack A row [B_N][GK] f16 (one block per b)
// cols 0..1023 = 0.5*x_hat ; cols 1024.. = 0.5*one_hot(z)
__global__ __launch_bounds__(256) void pack_x_kernel(
    const float* __restrict__ x, const int* __restrict__ zlab,
    ushort_t* __restrict__ A, float* __restrict__ inv_x) {
    const int b = blockIdx.x, t = threadIdx.x;
    const int lane = t & 63, wid = t >> 6;
    float4 v = reinterpret_cast<const float4*>(x + (size_t)b * X_N)[t];
    float ss = v.x*v.x + v.y*v.y + v.z*v.z + v.w*v.w;
    #pragma unroll
    for (int s = 32; s > 0; s >>= 1) ss += __shfl_xor(ss, s, 64);
    __shared__ float red[4];
    if (lane == 0) red[wid] = ss;
    __syncthreads();
    float inv = 1.0f / fmaxf(sqrtf(red[0] + red[1] + red[2] + red[3]), 1e-12f);
    if (t == 0) inv_x[b] = inv;
    float h = 0.5f * inv;
    ushort_t o1[4] = { f2h(v.x*h), f2h(v.y*h), f2h(v.z*h), f2h(v.w*h) };
    *reinterpret_cast<uint2*>(A + (size_t)b * GK + t * 4) = *reinterpret_cast<uint2*>(o1);
    int zb = zlab[b];
    ushort_t o2[4] = { 0, 0, 0, 0 };
    int base = t * 4;
    if (zb >= base && zb < base + 4) o2[zb - base] = (ushort_t)0x3800;  // f16 0.5
    *reinterpret_cast<uint2*>(A + (size_t)b * GK + X_N + t * 4) = *reinterpret_cast<uint2*>(o2);
}

// fused: row-norms of wxw/wzw + pack B row [Y_N][GK] f16 (one block per y)
__global__ __launch_bounds__(256) void pack_w_kernel(
    const float* __restrict__ wxw, const float* __restrict__ wzw,
    ushort_t* __restrict__ Bm, float* __restrict__ inv_wx, float* __restrict__ inv_wz) {
    const int y = blockIdx.x, t = threadIdx.x;
    const int lane = t & 63, wid = t >> 6;
    float4 a = reinterpret_cast<const float4*>(wxw + (size_t)y * X_N)[t];
    float4 zv = make_float4(0.f, 0.f, 0.f, 0.f);
    if (t < 250) zv = reinterpret_cast<const float4*>(wzw + (size_t)y * Z_N)[t];
    float s1 = a.x*a.x + a.y*a.y + a.z*a.z + a.w*a.w;
    float s2 = zv.x*zv.x + zv.y*zv.y + zv.z*zv.z + zv.w*zv.w;
    #pragma unroll
    for (int s = 32; s > 0; s >>= 1) {
        s1 += __shfl_xor(s1, s, 64);
        s2 += __shfl_xor(s2, s, 64);
    }
    __shared__ float r1[4], r2[4];
    if (lane == 0) { r1[wid] = s1; r2[wid] = s2; }
    __syncthreads();
    float inv1 = 1.0f / fmaxf(sqrtf(r1[0] + r1[1] + r1[2] + r1[3]), 1e-12f);
    float inv2 = 1.0f / fmaxf(sqrtf(r2[0] + r2[1] + r2[2] + r2[3]), 1e-12f);
    ushort_t o1[4] = { f2h(a.x*inv1), f2h(a.y*inv1), f2h(a.z*inv1), f2h(a.w*inv1) };
    *reinterpret_cast<uint2*>(Bm + (size_t)y * GK + t * 4) = *reinterpret_cast<uint2*>(o1);
    ushort_t o2[4] = { 0, 0, 0, 0 };
    if (t < 250) { o2[0]=f2h(zv.x*inv2); o2[1]=f2h(zv.y*inv2); o2[2]=f2h(zv.z*inv2); o2[3]=f2h(zv.w*inv2); }
    *reinterpret_cast<uint2*>(Bm + (size_t)y * GK + X_N + t * 4) = *reinterpret_cast<uint2*>(o2);
    if (t == 0) { inv_wx[y] = inv1; inv_wz[y] = inv2; }
}

// f16 MFMA GEMM, 256x256 tile, BK=32, 4-buffer (3-deep) counted-vmcnt pipeline:
// 12 loads/wave in flight; the wait for tile k+1 trails its issue by 2 iterations.
__global__ __launch_bounds__(512, 1) void mm256_kernel(const ushort_t* __restrict__ A,
                                                       const ushort_t* __restrict__ Bm,
                                                       ushort_t* __restrict__ S) {
    // [buf][mat][slot = g*256 + row][8 f16]; g in [0,4) covers BK=32; 4x32KB = 128KB
    __shared__ __align__(16) _Float16 lds[4][2][1024][8];
    const int t = threadIdx.x;
    const int wid = t >> 6, lane = t & 63;
    const int bid = blockIdx.x;
    const int lb = (bid & 7) * 32 + (bid >> 3);   // bijective: 256 % 8 == 0
    const int mt = lb & 3, nt = lb >> 2;
    const int b0 = mt * 256, y0 = nt * 256;
    const int wr = wid >> 2, wc = wid & 3;        // 2 x 4 waves
    const int r = lane & 15, gq = lane >> 4;
    const int NK = GK / 32;                        // 64 K-tiles

    f32x4 acc[8][4];
    #pragma unroll
    for (int i = 0; i < 8; ++i)
        #pragma unroll
        for (int j = 0; j < 4; ++j) acc[i][j] = (f32x4){0.f, 0.f, 0.f, 0.f};

    // 4 gload_lds per thread per stage (2 A + 2 B)
    auto stage = [&](int buf, int k0) {
        #pragma unroll
        for (int rr = 0; rr < 2; ++rr) {
            int s = rr * 512 + t;
            int row = s & 255, g = s >> 8;     // g in [0,4)
            GLOAD16(A  + (size_t)(b0 + row) * GK + k0 + g * 8, &lds[buf][0][s][0]);
            GLOAD16(Bm + (size_t)(y0 + row) * GK + k0 + g * 8, &lds[buf][1][s][0]);
        }
    };

    // prologue: 3-deep prefetch; wait only for tile 0 (8 newer stay in flight)
    stage(0, 0);
    stage(1, 32);
    stage(2, 64);
    asm volatile("s_waitcnt vmcnt(8)" ::: "memory");
    __builtin_amdgcn_s_barrier();
    asm volatile("" ::: "memory");

    for (int ks = 0; ks < NK; ++ks) {
        const int cur = ks & 3;
        // compute tile ks from buf[cur] (landed; all waves' loads done per barrier)
        f16x8 bF[4];
        #pragma unroll
        for (int nf = 0; nf < 4; ++nf)
            bF[nf] = *reinterpret_cast<const f16x8*>(
                &lds[cur][1][gq * 256 + wc * 64 + nf * 16 + r][0]);
        __builtin_amdgcn_s_setprio(1);
        #pragma unroll
        for (int mf = 0; mf < 8; ++mf) {
            f16x8 aF = *reinterpret_cast<const f16x8*>(
                &lds[cur][0][gq * 256 + wr * 128 + mf * 16 + r][0]);
            #pragma unroll
            for (int nf = 0; nf < 4; ++nf)
                acc[mf][nf] = __builtin_amdgcn_mfma_f32_16x16x32_f16(
                    aF, bF[nf], acc[mf][nf], 0, 0, 0);
        }
        __builtin_amdgcn_s_setprio(0);
        if (ks == NK - 1) break;

        __builtin_amdgcn_s_barrier();            // all waves done reading buf[cur]
        asm volatile("" ::: "memory");
        if (ks + 3 < NK) {
            stage((ks + 3) & 3, (ks + 3) * 32);  // reuse the buffer consumed at ks-1
            asm volatile("s_waitcnt vmcnt(8)" ::: "memory");  // tile ks+1 landed
        } else if (ks + 3 == NK) {
            asm volatile("s_waitcnt vmcnt(4)" ::: "memory");  // tile ks+1 landed (tail)
        } else {
            asm volatile("s_waitcnt vmcnt(0)" ::: "memory");  // last tile landed
        }
        __builtin_amdgcn_s_barrier();            // all waves' tile-(ks+1) loads landed
        asm volatile("" ::: "memory");
    }

    // C layout: col = lane&15, row = (lane>>4)*4 + reg
    #pragma unroll
    for (int mf = 0; mf < 8; ++mf) {
        int bg = b0 + wr * 128 + mf * 16 + gq * 4;
        #pragma unroll
        for (int nf = 0; nf < 4; ++nf) {
            int yg = y0 + wc * 64 + nf * 16 + r;
            f32x4 c = acc[mf][nf];
            #pragma unroll
            for (int q = 0; q < 4; ++q)
                S[(size_t)(bg + q) * Y_N + yg] = f2h(c[q]);
        }
    }
}

// per-row: approx max + candidate collection (per-row slab, LDS atomics only)
__global__ __launch_bounds__(256) void scan_kernel(
    const ushort_t* __restrict__ scores, const unsigned long long* __restrict__ mbits,
    const int* __restrict__ ctr, unsigned* __restrict__ gcand, int* __restrict__ ccnt) {
    const int b = blockIdx.x, t = threadIdx.x;
    const int lane = t & 63, wid = t >> 6;
    const uint4* srow = reinterpret_cast<const uint4*>(scores + (size_t)b * Y_N);

    float vmax = -1e30f, mmax = -1e30f;
    for (int c = t; c < Y_N / 8; c += 256) {
        uint4 pk = srow[c];
        int yb = c * 8;
        unsigned m8 = (unsigned)((mbits[yb >> 6] >> (yb & 63)) & 0xFFull);
        unsigned w[4] = {pk.x, pk.y, pk.z, pk.w};
        #pragma unroll
        for (int j = 0; j < 4; ++j) {
            float v0 = h2f(w[j] & 0xFFFFu);
            float v1 = h2f(w[j] >> 16);
            vmax = fmaxf(vmax, fmaxf(v0, v1));
            mmax = fmaxf(mmax, v0 * (float)((m8 >> (2 * j)) & 1u));
            mmax = fmaxf(mmax, v1 * (float)((m8 >> (2 * j + 1)) & 1u));
        }
    }
    #pragma unroll
    for (int s = 32; s > 0; s >>= 1) {
        vmax = fmaxf(vmax, __shfl_xor(vmax, s, 64));
        mmax = fmaxf(mmax, __shfl_xor(mmax, s, 64));
    }
    __shared__ float rv[4], rm[4];
    __shared__ int nA_s, nB_s;
    __shared__ int cA[256], cB[256];
    if (lane == 0) { rv[wid] = vmax; rm[wid] = mmax; }
    if (t == 0) { nA_s = 0; nB_s = 0; }
    __syncthreads();
    float tA = fmaxf(fmaxf(rv[0], rv[1]), fmaxf(rv[2], rv[3])) - MARGIN;
    float tB = fmaxf(fmaxf(rm[0], rm[1]), fmaxf(rm[2], rm[3])) - MARGIN;
    bool anyu = ctr[0] > 0;

    for (int c = t; c < Y_N / 8; c += 256) {
        uint4 pk = srow[c];
        int yb = c * 8;
        unsigned m8 = (unsigned)((mbits[yb >> 6] >> (yb & 63)) & 0xFFull);
        unsigned w[4] = {pk.x, pk.y, pk.z, pk.w};
        #pragma unroll
        for (int j = 0; j < 8; ++j) {
            float v = h2f((j & 1) ? (w[j >> 1] >> 16) : (w[j >> 1] & 0xFFFFu));
            if (v >= tA) { int p = atomicAdd(&nA_s, 1); if (p < 256) cA[p] = yb + j; }
            if (anyu && ((m8 >> j) & 1u) && v >= tB) {
                int p = atomicAdd(&nB_s, 1); if (p < 256) cB[p] = yb + j;
            }
        }
    }
    __syncthreads();
    int nA = min(nA_s, 256), nB = min(nB_s, 256);
    unsigned* slab = gcand + (size_t)b * 512;
    for (int i = t; i < nA; i += 256) slab[i] = (unsigned)cA[i];
    for (int i = t; i < nB; i += 256) slab[256 + i] = (unsigned)cB[i];
    if (t == 0) ccnt[b] = nA | (nB << 16);
}

// per-row: exact fp32 rescore (A list, judge, conditional B list) + finalize
__global__ __launch_bounds__(256) void rescore_kernel(
    const unsigned* __restrict__ gcand, const int* __restrict__ ccnt,
    const float* __restrict__ x, const float* __restrict__ inv_x,
    const float* __restrict__ wxw, const float* __restrict__ inv_wx,
    const float* __restrict__ wzw, const float* __restrict__ inv_wz,
    const int* __restrict__ zlab, const float* __restrict__ y_thr,
    const float* __restrict__ y_age, const int* __restrict__ ctr,
    int* final_idx, int* cnt, unsigned* segmin, int* zcnt,
    float* __restrict__ out_maxresp) {
    const int b = blockIdx.x, t = threadIdx.x;
    const int lane = t & 63, wid = t >> 6;
    int pc = ccnt[b];
    int nA = pc & 0xFFFF, nB = pc >> 16;
    int zb = zlab[b];
    float invx = inv_x[b];
    const unsigned* slab = gcand + (size_t)b * 512;

    const float4* xr = reinterpret_cast<const float4*>(x + (size_t)b * X_N);
    float4 xv[4];
    #pragma unroll
    for (int j = 0; j < 4; ++j) xv[j] = xr[j * 64 + lane];

    __shared__ unsigned long long red[4];
    __shared__ unsigned long long sPM;
    __shared__ int sTakeA;

    // ---- list A ----
    unsigned long long bA = 0ull;
    for (int c = wid; c < nA; c += 8) {
        int y1 = (int)slab[c];
        int c2 = c + 4;
        bool h2 = c2 < nA;
        int y2 = (int)slab[h2 ? c2 : c];
        const float4* w1 = reinterpret_cast<const float4*>(wxw + (size_t)y1 * X_N);
        const float4* w2 = reinterpret_cast<const float4*>(wxw + (size_t)y2 * X_N);
        float d1 = 0.f, d2 = 0.f;
        #pragma unroll
        for (int j = 0; j < 4; ++j) {
            float4 a1 = w1[j * 64 + lane];
            float4 a2 = w2[j * 64 + lane];
            d1 += xv[j].x*a1.x + xv[j].y*a1.y + xv[j].z*a1.z + xv[j].w*a1.w;
            d2 += xv[j].x*a2.x + xv[j].y*a2.y + xv[j].z*a2.z + xv[j].w*a2.w;
        }
        #pragma unroll
        for (int s = 32; s > 0; s >>= 1) {
            d1 += __shfl_xor(d1, s, 64);
            d2 += __shfl_xor(d2, s, 64);
        }
        float v1 = 0.5f*invx*inv_wx[y1]*d1 + 0.5f*inv_wz[y1]*wzw[(size_t)y1*Z_N + zb];
        unsigned long long p1 = pack_vi(v1, y1);
        bA = (p1 > bA) ? p1 : bA;
        if (h2) {
            float v2 = 0.5f*invx*inv_wx[y2]*d2 + 0.5f*inv_wz[y2]*wzw[(size_t)y2*Z_N + zb];
            unsigned long long p2 = pack_vi(v2, y2);
            bA = (p2 > bA) ? p2 : bA;
        }
    }
    if (lane == 0) red[wid] = bA;
    __syncthreads();
    if (t == 0) {
        unsigned long long pm = red[0];
        #pragma unroll
        for (int j = 1; j < 4; ++j) pm = (red[j] > pm) ? red[j] : pm;
        sPM = pm;
        unsigned enc = (unsigned)(pm >> 32);
        int idx = (int)(0xFFFFFFFFu - (unsigned)(pm & 0xFFFFFFFFull));
        float mresp = dec_f(enc);
        out_maxresp[b] = mresp;
        bool judge = (mresp > y_thr[idx]) || (y_age[idx] < 1.0f);
        bool anyu = ctr[0] > 0;
        sTakeA = (judge || !anyu) ? 1 : 0;
    }
    __syncthreads();

    // ---- list B only when fallback needed ----
    if (!sTakeA) {
        unsigned long long bB = 0ull;
        for (int c = wid; c < nB; c += 8) {
            int y1 = (int)slab[256 + c];
            int c2 = c + 4;
            bool h2 = c2 < nB;
            int y2 = (int)slab[256 + (h2 ? c2 : c)];
            const float4* w1 = reinterpret_cast<const float4*>(wxw + (size_t)y1 * X_N);
            const float4* w2 = reinterpret_cast<const float4*>(wxw + (size_t)y2 * X_N);
            float d1 = 0.f, d2 = 0.f;
            #pragma unroll
            for (int j = 0; j < 4; ++j) {
                float4 a1 = w1[j * 64 + lane];
                float4 a2 = w2[j * 64 + lane];
                d1 += xv[j].x*a1.x + xv[j].y*a1.y + xv[j].z*a1.z + xv[j].w*a1.w;
                d2 += xv[j].x*a2.x + xv[j].y*a2.y + xv[j].z*a2.z + xv[j].w*a2.w;
            }
            #pragma unroll
            for (int s = 32; s > 0; s >>= 1) {
                d1 += __shfl_xor(d1, s, 64);
                d2 += __shfl_xor(d2, s, 64);
            }
            float v1 = 0.5f*invx*inv_wx[y1]*d1 + 0.5f*inv_wz[y1]*wzw[(size_t)y1*Z_N + zb];
            unsigned long long p1 = pack_vi(v1, y1);
            bB = (p1 > bB) ? p1 : bB;
            if (h2) {
                float v2 = 0.5f*invx*inv_wx[y2]*d2 + 0.5f*inv_wz[y2]*wzw[(size_t)y2*Z_N + zb];
                unsigned long long p2 = pack_vi(v2, y2);
                bB = (p2 > bB) ? p2 : bB;
            }
        }
        if (lane == 0) red[wid] = bB;
    }
    __syncthreads();
    if (t == 0) {
        unsigned long long pm = sPM;
        unsigned enc = (unsigned)(pm >> 32);
        int idx = (int)(0xFFFFFFFFu - (unsigned)(pm & 0xFFFFFFFFull));
        int fin;
        if (sTakeA) {
            fin = idx;
        } else if (nB > 0) {
            unsigned long long pf = red[0];
            #pragma unroll
            for (int j = 1; j < 4; ++j) pf = (red[j] > pf) ? red[j] : pf;
            fin = (int)(0xFFFFFFFFu - (unsigned)(pf & 0xFFFFFFFFull));
        } else {
            fin = ctr[2];   // all-unact-nonpositive: ref argmax lands on first activated
        }
        final_idx[b] = fin;
        atomicAdd(&cnt[fin], 1);
        atomicMin(&segmin[fin], enc);
        atomicAdd(&zcnt[zb], 1);
    }
}

__global__ __launch_bounds__(256) void wx_out_kernel(
    const float* __restrict__ wxw, const float* __restrict__ inv_wx,
    const float* __restrict__ x, const float* __restrict__ inv_x,
    const int* __restrict__ final_idx, const int* __restrict__ cnt,
    const float* __restrict__ y_age, float* __restrict__ outw) {
    int j = blockIdx.x;
    int t = threadIdx.x;
    __shared__ int s_b[1024];
    __shared__ int s_n;
    if (t == 0) s_n = 0;
    __syncthreads();
    int c = cnt[j];
    if (c > 0) {
        for (int b = t; b < B_N; b += 256)
            if (final_idx[b] == j) { int p = atomicAdd(&s_n, 1); s_b[p] = b; }
    }
    __syncthreads();
    float inv = inv_wx[j];
    float lr = 1.0f / (y_age[j] + 1.0f);
    float fc = (float)c;
    float dv = (c > 0) ? fc : 1.0f;
    int n = s_n;
    float4 w = *reinterpret_cast<const float4*>(wxw + (size_t)j * X_N + t * 4);
    float4 wn = make_float4(w.x*inv, w.y*inv, w.z*inv, w.w*inv);
    if (c > 0) {
        float4 s = make_float4(0.f, 0.f, 0.f, 0.f);
        for (int m = 0; m < n; ++m) {
            int b = s_b[m];
            float ix = inv_x[b];
            float4 xv = *reinterpret_cast<const float4*>(x + (size_t)b * X_N + t * 4);
            s.x += xv.x * ix; s.y += xv.y * ix; s.z += xv.z * ix; s.w += xv.w * ix;
        }
        float f = lr / dv;
        wn.x += f * (s.x - fc * wn.x);
        wn.y += f * (s.y - fc * wn.y);
        wn.z += f * (s.z - fc * wn.z);
        wn.w += f * (s.w - fc * wn.w);
    }
    *reinterpret_cast<float4*>(outw + (size_t)j * X_N + t * 4) = wn;
}

__global__ __launch_bounds__(256) void wz_out_kernel(
    const float* __restrict__ wzw, const float* __restrict__ inv_wz,
    const int* __restrict__ zlab, const int* __restrict__ final_idx,
    const int* __restrict__ cnt, const float* __restrict__ y_age,
    float* __restrict__ outw) {
    int j = blockIdx.x;
    int t = threadIdx.x;
    __shared__ int s_c[1024];
    __shared__ int s_n;
    if (t == 0) s_n = 0;
    __syncthreads();
    int c = cnt[j];
    if (c > 0) {
        for (int b = t; b < B_N; b += 256)
            if (final_idx[b] == j) { int p = atomicAdd(&s_n, 1); s_c[p] = zlab[b]; }
    }
    __syncthreads();
    if (t >= 250) return;
    float inv = inv_wz[j];
    float lr = 1.0f / (y_age[j] + 1.0f);
    float fc = (float)c;
    float dv = (c > 0) ? fc : 1.0f;
    int n = s_n;
    float4 w = *reinterpret_cast<const float4*>(wzw + (size_t)j * Z_N + t * 4);
    float4 wn = make_float4(w.x*inv, w.y*inv, w.z*inv, w.w*inv);
    if (c > 0) {
        float4 s = make_float4(0.f, 0.f, 0.f, 0.f);
        for (int m = 0; m < n; ++m) {
            int d = s_c[m] - t * 4;
            if (d == 0) s.x += 1.f;
            else if (d == 1) s.y += 1.f;
            else if (d == 2) s.z += 1.f;
            else if (d == 3) s.w += 1.f;
        }
        float f = lr / dv;
        wn.x += f * (s.x - fc * wn.x);
        wn.y += f * (s.y - fc * wn.y);
        wn.z += f * (s.z - fc * wn.z);
        wn.w += f * (s.w - fc * wn.w);
    }
    *reinterpret_cast<float4*>(outw + (size_t)j * Z_N + t * 4) = wn;
}

// fused: row-norm of U + U update (row held in registers; one read, one write)
__global__ __launch_bounds__(256) void u_out_kernel(
    const float* __restrict__ uw, const int* __restrict__ zlab,
    const int* __restrict__ final_idx, const int* __restrict__ zcnt,
    const float* __restrict__ z_age, float* __restrict__ outw) {
    int cz = blockIdx.x;
    int t = threadIdx.x;
    const int lane = t & 63, wid = t >> 6;
    __shared__ int s_w[1024];
    __shared__ int s_n;
    __shared__ float rss[4];
    if (t == 0) s_n = 0;

    const float4* rowp4 = reinterpret_cast<const float4*>(uw + (size_t)cz * Y_N);
    float4 u[16];
    float ss = 0.f;
    #pragma unroll
    for (int p = 0; p < 16; ++p) {
        u[p] = rowp4[p * 256 + t];
        ss += u[p].x*u[p].x + u[p].y*u[p].y + u[p].z*u[p].z + u[p].w*u[p].w;
    }
    #pragma unroll
    for (int s = 32; s > 0; s >>= 1) ss += __shfl_xor(ss, s, 64);
    if (lane == 0) rss[wid] = ss;
    __syncthreads();
    float inv = 1.0f / fmaxf(sqrtf(rss[0] + rss[1] + rss[2] + rss[3]), 1e-12f);

    int c = zcnt[cz];
    if (c > 0) {
        for (int b = t; b < B_N; b += 256)
            if (zlab[b] == cz) { int p = atomicAdd(&s_n, 1); s_w[p] = final_idx[b]; }
    }
    __syncthreads();
    float zlr = 1.0f / (z_age[cz] + 1.0f);
    float fc = (float)c;
    float dv = (c > 0) ? fc : 1.0f;
    float f = zlr / dv;
    int n = s_n;
    float* outp = outw + (size_t)cz * Y_N;
    #pragma unroll
    for (int p = 0; p < 16; ++p) {
        int e4 = p * 256 + t;
        float4 un = make_float4(u[p].x*inv, u[p].y*inv, u[p].z*inv, u[p].w*inv);
        if (c > 0) {
            float4 s = make_float4(0.f, 0.f, 0.f, 0.f);
            for (int m = 0; m < n; ++m) {
                int d = s_w[m] - e4 * 4;
                if (d == 0) s.x += 1.f;
                else if (d == 1) s.y += 1.f;
                else if (d == 2) s.z += 1.f;
                else if (d == 3) s.w += 1.f;
            }
            un.x += f * (s.x - fc * un.x);
            un.y += f * (s.y - fc * un.y);
            un.z += f * (s.z - fc * un.z);
            un.w += f * (s.w - fc * un.w);
        }
        *reinterpret_cast<float4*>(outp + e4 * 4) = un;
    }
}

__global__ void thr_age_kernel(const int* __restrict__ cnt, const unsigned* __restrict__ segmin,
                               const float* __restrict__ y_age, const float* __restrict__ y_thr,
                               float* __restrict__ out_thr, float* __restrict__ out_age,
                               int* ctr) {
    int j = blockIdx.x * 256 + threadIdx.x;
    int c = cnt[j];
    float age = y_age[j];
    float thr = y_thr[j];
    float tn = thr;
    if (c > 0) {
        float lr = 1.0f / (age + 1.0f);
        float smin = dec_f(segmin[j]);
        float ycur = fminf(smin, 3.0f);
        if (ycur > 2.0f) ycur = 0.0f;
        tn = lr * ycur + (1.0f - lr) * thr;
    }
    out_thr[j] = tn;
    float an = age + (float)c;
    out_age[j] = an;
    unsigned long long m = __ballot(an >= 1.0f ? 1 : 0);
    if ((threadIdx.x & 63) == 0) atomicAdd(ctr + 1, (int)__popcll(m));
}

__global__ void zage_act_kernel(const int* __restrict__ zcnt, const float* __restrict__ z_age,
                                const int* __restrict__ ctr, float* __restrict__ out_zage,
                                float* __restrict__ out_act) {
    int i = blockIdx.x * 256 + threadIdx.x;
    if (i < Z_N) out_zage[i] = z_age[i] + (float)zcnt[i];
    if (i == 0) out_act[0] = (float)ctr[1];
}

extern "C" void kernel_launch(void* const* d_in, const int* in_sizes, int n_in,
                              void* d_out, int out_size, void* d_ws, size_t ws_size,
                              hipStream_t stream) {
    const float* x     = (const float*)d_in[0];
    const int*   z     = (const int*)d_in[1];
    const float* wxw   = (const float*)d_in[2];
    const float* wzw   = (const float*)d_in[3];
    const float* uw    = (const float*)d_in[4];
    const float* y_age = (const float*)d_in[5];
    const float* z_age = (const float*)d_in[6];
    const float* y_thr = (const float*)d_in[7];
    float* out = (float*)d_out;
    float* ws  = (float*)d_ws;
    char*  ob  = (char*)d_out;

    float* inv_x  = ws + WS_INV_X;
    float* inv_wx = ws + WS_INV_WX;
    float* inv_wz = ws + WS_INV_WZ;
    int* fidx = (int*)(ws + WS_FIDX);
    int* cnt  = (int*)(ws + WS_CNT);
    int* zcnt = (int*)(ws + WS_ZCNT);
    unsigned* segmin = (unsigned*)(ws + WS_SEGMIN);
    int* ctr = (int*)(ws + WS_CTR);
    unsigned long long* mbits = (unsigned long long*)(ws + WS_MBITS);
    int* ccnt = (int*)(ws + WS_CCNT);

    ushort_t* Bb = (ushort_t*)(ob + SCR_B_BYTES);
    ushort_t* Sc = (ushort_t*)(ob + SCR_S_BYTES);
    ushort_t* Ab = (ushort_t*)(ob + SCR_A_BYTES);
    unsigned* gcand = (unsigned*)(ob + SCR_CAND_BYTES);

    init_kernel<<<64, 256, 0, stream>>>(cnt, segmin, zcnt, ctr);
    unact_kernel<<<Y_N / 256, 256, 0, stream>>>(y_age, ctr, mbits);
    pack_x_kernel<<<B_N, 256, 0, stream>>>(x, z, Ab, inv_x);
    pack_w_kernel<<<Y_N, 256, 0, stream>>>(wxw, wzw, Bb, inv_wx, inv_wz);
    mm256_kernel<<<(B_N / 256) * (Y_N / 256), 512, 0, stream>>>(Ab, Bb, Sc);
    scan_kernel<<<B_N, 256, 0, stream>>>(Sc, mbits, ctr, gcand, ccnt);
    rescore_kernel<<<B_N, 256, 0, stream>>>(gcand, ccnt, x, inv_x, wxw, inv_wx, wzw, inv_wz,
                                            z, y_thr, y_age, ctr, fidx, cnt, segmin, zcnt,
                                            out + OFF_MAXRESP);
    wx_out_kernel<<<Y_N, 256, 0, stream>>>(wxw, inv_wx, x, inv_x, fidx, cnt, y_age, out + OFF_WX);
    wz_out_kernel<<<Y_N, 256, 0, stream>>>(wzw, inv_wz, z, fidx, cnt, y_age, out + OFF_WZ);
    u_out_kernel<<<Z_N, 256, 0, stream>>>(uw, z, fidx, zcnt, z_age, out + OFF_U);
    thr_age_kernel<<<Y_N / 256, 256, 0, stream>>>(cnt, segmin, y_age, y_thr,
                                                  out + OFF_THR, out + OFF_AGE, ctr);
    zage_act_kernel<<<4, 256, 0, stream>>>(zcnt, z_age, ctr, out + OFF_ZAGE, out + OFF_ACT);
}

// Round 9
// 259.027 us; speedup vs baseline: 1.4992x; 1.1185x over previous
//
#include <hip/hip_runtime.h>

#define B_N 1024
#define X_N 1024
#define Y_N 16384
#define Z_N 1000
#define KD  1024
#define MARGIN 0.004f

// output float offsets
#define OFF_ACT      0
#define OFF_MAXRESP  1
#define OFF_WX       1025
#define OFF_WZ       16778241
#define OFF_U        33162241
#define OFF_THR      49546241
#define OFF_AGE      49562625
#define OFF_ZAGE     49579009

// scratch in not-yet-written d_out regions (16B-aligned byte offsets)
#define SCR_B_BYTES    4112ull       /* Bb f16 32MB, in OFF_WX region */
#define SCR_S_BYTES    67112976ull   /* Sc f16 32MB, in OFF_WZ region */
#define SCR_A_BYTES    132648976ull  /* Ab f16 2MB, in OFF_U region */
#define SCR_CAND_BYTES 134746128ull  /* u32[1024][512] = 2MB, in OFF_U region */
#define SCR_WZT_BYTES  136843280ull  /* wzt f16 [1024 z-slots][Y_N] 32MB, in OFF_U region */

// ws float offsets
#define WS_INV_X    0
#define WS_INV_WX   1024
#define WS_INV_WZ   17408
#define WS_FIDX     38912   /* int[1024] */
#define WS_CNT      39936   /* int[16384] */
#define WS_ZCNT     56320   /* int[1024] */
#define WS_SEGMIN   57344   /* uint[16384] */
#define WS_CTR      73728   /* int[8]: [0]=unact_cnt [1]=act_cnt [2]=min_act_idx */
#define WS_MBITS    73736   /* u64[256] */
#define WS_CCNT     74248   /* int[1024] */

typedef unsigned short ushort_t;
typedef _Float16 f16x8 __attribute__((ext_vector_type(8)));
typedef float f32x4 __attribute__((ext_vector_type(4)));

__device__ __forceinline__ unsigned enc_f(float f) {
    unsigned u = __float_as_uint(f);
    return (u & 0x80000000u) ? ~u : (u | 0x80000000u);
}
__device__ __forceinline__ float dec_f(unsigned e) {
    unsigned u = (e & 0x80000000u) ? (e ^ 0x80000000u) : ~e;
    return __uint_as_float(u);
}
__device__ __forceinline__ unsigned long long pack_vi(float v, int y) {
    return ((unsigned long long)enc_f(v) << 32) |
           (unsigned long long)(0xFFFFFFFFu - (unsigned)y);
}
__device__ __forceinline__ ushort_t f2h(float f) {
    _Float16 h = (_Float16)f;           // RTNE
    ushort_t u; __builtin_memcpy(&u, &h, 2); return u;
}
__device__ __forceinline__ float h2f(unsigned lo16) {
    ushort_t u = (ushort_t)lo16; _Float16 h;
    __builtin_memcpy(&h, &u, 2); return (float)h;
}

#define GLOAD16(gp, lp) __builtin_amdgcn_global_load_lds( \
    (const __attribute__((address_space(1))) void*)(gp),  \
    (__attribute__((address_space(3))) void*)(lp), 16, 0, 0)

__global__ void init_kernel(int* cnt, unsigned* segmin, int* zcnt, int* ctr) {
    int i = blockIdx.x * 256 + threadIdx.x;
    if (i < Y_N) { cnt[i] = 0; segmin[i] = 0xFFFFFFFFu; }
    if (i < 1024) zcnt[i] = 0;
    if (i < 8) ctr[i] = (i == 2) ? 0x7FFFFFFF : 0;
}

__global__ void unact_kernel(const float* __restrict__ y_age, int* ctr,
                             unsigned long long* __restrict__ mbits) {
    int i = blockIdx.x * 256 + threadIdx.x;
    int a = (y_age[i] < 1.0f) ? 1 : 0;
    unsigned long long m = __ballot(a);
    int mi = a ? 0x7FFFFFFF : i;   // min index over ACTIVATED neurons
    #pragma unroll
    for (int s = 32; s > 0; s >>= 1) mi = min(mi, __shfl_xor(mi, s, 64));
    if ((threadIdx.x & 63) == 0) {
        atomicAdd(ctr, (int)__popcll(m));
        mbits[i >> 6] = m;
        if (mi != 0x7FFFFFFF) atomicMin(&ctr[2], mi);
    }
}

// fused: row-norm of x + pack A row [B_N][KD] f16 = x_hat (one block per b)
__global__ __launch_bounds__(256) void pack_x_kernel(
    const float* __restrict__ x, ushort_t* __restrict__ A, float* __restrict__ inv_x) {
    const int b = blockIdx.x, t = threadIdx.x;
    const int lane = t & 63, wid = t >> 6;
    float4 v = reinterpret_cast<const float4*>(x + (size_t)b * X_N)[t];
    float ss = v.x*v.x + v.y*v.y + v.z*v.z + v.w*v.w;
    #pragma unroll
    for (int s = 32; s > 0; s >>= 1) ss += __shfl_xor(ss, s, 64);
    __shared__ float red[4];
    if (lane == 0) red[wid] = ss;
    __syncthreads();
    float inv = 1.0f / fmaxf(sqrtf(red[0] + red[1] + red[2] + red[3]), 1e-12f);
    if (t == 0) inv_x[b] = inv;
    ushort_t o1[4] = { f2h(v.x*inv), f2h(v.y*inv), f2h(v.z*inv), f2h(v.w*inv) };
    *reinterpret_cast<uint2*>(A + (size_t)b * KD + t * 4) = *reinterpret_cast<uint2*>(o1);
}

// fused: row-norms of wxw/wzw + pack B row [Y_N][KD] f16 = wx_hat (one block per y)
__global__ __launch_bounds__(256) void pack_w_kernel(
    const float* __restrict__ wxw, const float* __restrict__ wzw,
    ushort_t* __restrict__ Bm, float* __restrict__ inv_wx, float* __restrict__ inv_wz) {
    const int y = blockIdx.x, t = threadIdx.x;
    const int lane = t & 63, wid = t >> 6;
    float4 a = reinterpret_cast<const float4*>(wxw + (size_t)y * X_N)[t];
    float4 zv = make_float4(0.f, 0.f, 0.f, 0.f);
    if (t < 250) zv = reinterpret_cast<const float4*>(wzw + (size_t)y * Z_N)[t];
    float s1 = a.x*a.x + a.y*a.y + a.z*a.z + a.w*a.w;
    float s2 = zv.x*zv.x + zv.y*zv.y + zv.z*zv.z + zv.w*zv.w;
    #pragma unroll
    for (int s = 32; s > 0; s >>= 1) {
        s1 += __shfl_xor(s1, s, 64);
        s2 += __shfl_xor(s2, s, 64);
    }
    __shared__ float r1[4], r2[4];
    if (lane == 0) { r1[wid] = s1; r2[wid] = s2; }
    __syncthreads();
    float inv1 = 1.0f / fmaxf(sqrtf(r1[0] + r1[1] + r1[2] + r1[3]), 1e-12f);
    float inv2 = 1.0f / fmaxf(sqrtf(r2[0] + r2[1] + r2[2] + r2[3]), 1e-12f);
    ushort_t o1[4] = { f2h(a.x*inv1), f2h(a.y*inv1), f2h(a.z*inv1), f2h(a.w*inv1) };
    *reinterpret_cast<uint2*>(Bm + (size_t)y * KD + t * 4) = *reinterpret_cast<uint2*>(o1);
    if (t == 0) { inv_wx[y] = inv1; inv_wz[y] = inv2; }
}

// LDS-tiled transpose: wzt[z][y] = 0.5 * wzw[y][z] * inv_wz[y]  (f16)
// block = 64z x 64y tile; grid = 16 z-tiles x 256 y-tiles
__global__ __launch_bounds__(256) void wzt_kernel(
    const float* __restrict__ wzw, const float* __restrict__ inv_wz,
    ushort_t* __restrict__ wzt) {
    const int bid = blockIdx.x;
    const int z0 = (bid & 15) * 64, y0 = (bid >> 4) * 64;
    const int t = threadIdx.x;
    __shared__ float tile[64][65];
    #pragma unroll
    for (int p = 0; p < 4; ++p) {
        int yr = p * 16 + (t >> 4);
        int z = z0 + (t & 15) * 4;
        float4 v = make_float4(0.f, 0.f, 0.f, 0.f);
        if (z + 3 < Z_N)
            v = *reinterpret_cast<const float4*>(wzw + (size_t)(y0 + yr) * Z_N + z);
        float s = 0.5f * inv_wz[y0 + yr];
        tile[(t & 15) * 4 + 0][yr] = v.x * s;
        tile[(t & 15) * 4 + 1][yr] = v.y * s;
        tile[(t & 15) * 4 + 2][yr] = v.z * s;
        tile[(t & 15) * 4 + 3][yr] = v.w * s;
    }
    __syncthreads();
    #pragma unroll
    for (int p = 0; p < 4; ++p) {
        int zr = p * 16 + (t >> 4);
        int yc = (t & 15) * 4;
        if (z0 + zr < 1024) {
            ushort_t o[4] = { f2h(tile[zr][yc]), f2h(tile[zr][yc + 1]),
                              f2h(tile[zr][yc + 2]), f2h(tile[zr][yc + 3]) };
            *reinterpret_cast<uint2*>(wzt + (size_t)(z0 + zr) * Y_N + y0 + yc) =
                *reinterpret_cast<uint2*>(o);
        }
    }
}

// f16 MFMA GEMM, 256x256 tile, K=1024, BK=32, 4-buffer 3-deep counted-vmcnt pipeline
__global__ __launch_bounds__(512, 1) void mm256_kernel(const ushort_t* __restrict__ A,
                                                       const ushort_t* __restrict__ Bm,
                                                       ushort_t* __restrict__ S) {
    __shared__ __align__(16) _Float16 lds[4][2][1024][8];
    const int t = threadIdx.x;
    const int wid = t >> 6, lane = t & 63;
    const int bid = blockIdx.x;
    const int lb = (bid & 7) * 32 + (bid >> 3);   // bijective: 256 % 8 == 0
    const int mt = lb & 3, nt = lb >> 2;
    const int b0 = mt * 256, y0 = nt * 256;
    const int wr = wid >> 2, wc = wid & 3;        // 2 x 4 waves
    const int r = lane & 15, gq = lane >> 4;
    const int NK = KD / 32;                        // 32 K-tiles

    f32x4 acc[8][4];
    #pragma unroll
    for (int i = 0; i < 8; ++i)
        #pragma unroll
        for (int j = 0; j < 4; ++j) acc[i][j] = (f32x4){0.f, 0.f, 0.f, 0.f};

    auto stage = [&](int buf, int k0) {
        #pragma unroll
        for (int rr = 0; rr < 2; ++rr) {
            int s = rr * 512 + t;
            int row = s & 255, g = s >> 8;     // g in [0,4)
            GLOAD16(A  + (size_t)(b0 + row) * KD + k0 + g * 8, &lds[buf][0][s][0]);
            GLOAD16(Bm + (size_t)(y0 + row) * KD + k0 + g * 8, &lds[buf][1][s][0]);
        }
    };

    stage(0, 0);
    stage(1, 32);
    stage(2, 64);
    asm volatile("s_waitcnt vmcnt(8)" ::: "memory");
    __builtin_amdgcn_s_barrier();
    asm volatile("" ::: "memory");

    for (int ks = 0; ks < NK; ++ks) {
        const int cur = ks & 3;
        f16x8 bF[4];
        #pragma unroll
        for (int nf = 0; nf < 4; ++nf)
            bF[nf] = *reinterpret_cast<const f16x8*>(
                &lds[cur][1][gq * 256 + wc * 64 + nf * 16 + r][0]);
        __builtin_amdgcn_s_setprio(1);
        #pragma unroll
        for (int mf = 0; mf < 8; ++mf) {
            f16x8 aF = *reinterpret_cast<const f16x8*>(
                &lds[cur][0][gq * 256 + wr * 128 + mf * 16 + r][0]);
            #pragma unroll
            for (int nf = 0; nf < 4; ++nf)
                acc[mf][nf] = __builtin_amdgcn_mfma_f32_16x16x32_f16(
                    aF, bF[nf], acc[mf][nf], 0, 0, 0);
        }
        __builtin_amdgcn_s_setprio(0);
        if (ks == NK - 1) break;

        __builtin_amdgcn_s_barrier();            // all waves done reading buf[cur]
        asm volatile("" ::: "memory");
        if (ks + 3 < NK) {
            stage((ks + 3) & 3, (ks + 3) * 32);
            asm volatile("s_waitcnt vmcnt(8)" ::: "memory");  // tile ks+1 landed
        } else if (ks + 3 == NK) {
            asm volatile("s_waitcnt vmcnt(4)" ::: "memory");
        } else {
            asm volatile("s_waitcnt vmcnt(0)" ::: "memory");
        }
        __builtin_amdgcn_s_barrier();
        asm volatile("" ::: "memory");
    }

    // C layout: col = lane&15, row = (lane>>4)*4 + reg; store 0.5*dot (x-part)
    #pragma unroll
    for (int mf = 0; mf < 8; ++mf) {
        int bg = b0 + wr * 128 + mf * 16 + gq * 4;
        #pragma unroll
        for (int nf = 0; nf < 4; ++nf) {
            int yg = y0 + wc * 64 + nf * 16 + r;
            f32x4 c = acc[mf][nf];
            #pragma unroll
            for (int q = 0; q < 4; ++q)
                S[(size_t)(bg + q) * Y_N + yg] = f2h(0.5f * c[q]);
        }
    }
}

// per-row: v = score_x + wzt[zb][y]; approx max + candidate collection
__global__ __launch_bounds__(256) void scan_kernel(
    const ushort_t* __restrict__ scores, const ushort_t* __restrict__ wzt,
    const int* __restrict__ zlab, const unsigned long long* __restrict__ mbits,
    const int* __restrict__ ctr, unsigned* __restrict__ gcand, int* __restrict__ ccnt) {
    const int b = blockIdx.x, t = threadIdx.x;
    const int lane = t & 63, wid = t >> 6;
    const uint4* srow = reinterpret_cast<const uint4*>(scores + (size_t)b * Y_N);
    const uint4* wrow = reinterpret_cast<const uint4*>(wzt + (size_t)zlab[b] * Y_N);

    float vmax = -1e30f, mmax = -1e30f;
    for (int c = t; c < Y_N / 8; c += 256) {
        uint4 pk = srow[c];
        uint4 wz = wrow[c];
        int yb = c * 8;
        unsigned m8 = (unsigned)((mbits[yb >> 6] >> (yb & 63)) & 0xFFull);
        unsigned w[4] = {pk.x, pk.y, pk.z, pk.w};
        unsigned q[4] = {wz.x, wz.y, wz.z, wz.w};
        #pragma unroll
        for (int j = 0; j < 4; ++j) {
            float v0 = h2f(w[j] & 0xFFFFu) + h2f(q[j] & 0xFFFFu);
            float v1 = h2f(w[j] >> 16) + h2f(q[j] >> 16);
            vmax = fmaxf(vmax, fmaxf(v0, v1));
            mmax = fmaxf(mmax, v0 * (float)((m8 >> (2 * j)) & 1u));
            mmax = fmaxf(mmax, v1 * (float)((m8 >> (2 * j + 1)) & 1u));
        }
    }
    #pragma unroll
    for (int s = 32; s > 0; s >>= 1) {
        vmax = fmaxf(vmax, __shfl_xor(vmax, s, 64));
        mmax = fmaxf(mmax, __shfl_xor(mmax, s, 64));
    }
    __shared__ float rv[4], rm[4];
    __shared__ int nA_s, nB_s;
    __shared__ int cA[256], cB[256];
    if (lane == 0) { rv[wid] = vmax; rm[wid] = mmax; }
    if (t == 0) { nA_s = 0; nB_s = 0; }
    __syncthreads();
    float tA = fmaxf(fmaxf(rv[0], rv[1]), fmaxf(rv[2], rv[3])) - MARGIN;
    float tB = fmaxf(fmaxf(rm[0], rm[1]), fmaxf(rm[2], rm[3])) - MARGIN;
    bool anyu = ctr[0] > 0;

    for (int c = t; c < Y_N / 8; c += 256) {
        uint4 pk = srow[c];
        uint4 wz = wrow[c];
        int yb = c * 8;
        unsigned m8 = (unsigned)((mbits[yb >> 6] >> (yb & 63)) & 0xFFull);
        unsigned w[4] = {pk.x, pk.y, pk.z, pk.w};
        unsigned q[4] = {wz.x, wz.y, wz.z, wz.w};
        #pragma unroll
        for (int j = 0; j < 8; ++j) {
            unsigned sw = (j & 1) ? (w[j >> 1] >> 16) : (w[j >> 1] & 0xFFFFu);
            unsigned qw = (j & 1) ? (q[j >> 1] >> 16) : (q[j >> 1] & 0xFFFFu);
            float v = h2f(sw) + h2f(qw);
            if (v >= tA) { int p = atomicAdd(&nA_s, 1); if (p < 256) cA[p] = yb + j; }
            if (anyu && ((m8 >> j) & 1u) && v >= tB) {
                int p = atomicAdd(&nB_s, 1); if (p < 256) cB[p] = yb + j;
            }
        }
    }
    __syncthreads();
    int nA = min(nA_s, 256), nB = min(nB_s, 256);
    unsigned* slab = gcand + (size_t)b * 512;
    for (int i = t; i < nA; i += 256) slab[i] = (unsigned)cA[i];
    for (int i = t; i < nB; i += 256) slab[256 + i] = (unsigned)cB[i];
    if (t == 0) ccnt[b] = nA | (nB << 16);
}

// per-row: exact fp32 rescore (A list, judge, conditional B list) + finalize
__global__ __launch_bounds__(256) void rescore_kernel(
    const unsigned* __restrict__ gcand, const int* __restrict__ ccnt,
    const float* __restrict__ x, const float* __restrict__ inv_x,
    const float* __restrict__ wxw, const float* __restrict__ inv_wx,
    const float* __restrict__ wzw, const float* __restrict__ inv_wz,
    const int* __restrict__ zlab, const float* __restrict__ y_thr,
    const float* __restrict__ y_age, const int* __restrict__ ctr,
    int* final_idx, int* cnt, unsigned* segmin, int* zcnt,
    float* __restrict__ out_maxresp) {
    const int b = blockIdx.x, t = threadIdx.x;
    const int lane = t & 63, wid = t >> 6;
    int pc = ccnt[b];
    int nA = pc & 0xFFFF, nB = pc >> 16;
    int zb = zlab[b];
    float invx = inv_x[b];
    const unsigned* slab = gcand + (size_t)b * 512;

    const float4* xr = reinterpret_cast<const float4*>(x + (size_t)b * X_N);
    float4 xv[4];
    #pragma unroll
    for (int j = 0; j < 4; ++j) xv[j] = xr[j * 64 + lane];

    __shared__ unsigned long long red[4];
    __shared__ unsigned long long sPM;
    __shared__ int sTakeA;

    unsigned long long bA = 0ull;
    for (int c = wid; c < nA; c += 8) {
        int y1 = (int)slab[c];
        int c2 = c + 4;
        bool h2 = c2 < nA;
        int y2 = (int)slab[h2 ? c2 : c];
        const float4* w1 = reinterpret_cast<const float4*>(wxw + (size_t)y1 * X_N);
        const float4* w2 = reinterpret_cast<const float4*>(wxw + (size_t)y2 * X_N);
        float d1 = 0.f, d2 = 0.f;
        #pragma unroll
        for (int j = 0; j < 4; ++j) {
            float4 a1 = w1[j * 64 + lane];
            float4 a2 = w2[j * 64 + lane];
            d1 += xv[j].x*a1.x + xv[j].y*a1.y + xv[j].z*a1.z + xv[j].w*a1.w;
            d2 += xv[j].x*a2.x + xv[j].y*a2.y + xv[j].z*a2.z + xv[j].w*a2.w;
        }
        #pragma unroll
        for (int s = 32; s > 0; s >>= 1) {
            d1 += __shfl_xor(d1, s, 64);
            d2 += __shfl_xor(d2, s, 64);
        }
        float v1 = 0.5f*invx*inv_wx[y1]*d1 + 0.5f*inv_wz[y1]*wzw[(size_t)y1*Z_N + zb];
        unsigned long long p1 = pack_vi(v1, y1);
        bA = (p1 > bA) ? p1 : bA;
        if (h2) {
            float v2 = 0.5f*invx*inv_wx[y2]*d2 + 0.5f*inv_wz[y2]*wzw[(size_t)y2*Z_N + zb];
            unsigned long long p2 = pack_vi(v2, y2);
            bA = (p2 > bA) ? p2 : bA;
        }
    }
    if (lane == 0) red[wid] = bA;
    __syncthreads();
    if (t == 0) {
        unsigned long long pm = red[0];
        #pragma unroll
        for (int j = 1; j < 4; ++j) pm = (red[j] > pm) ? red[j] : pm;
        sPM = pm;
        unsigned enc = (unsigned)(pm >> 32);
        int idx = (int)(0xFFFFFFFFu - (unsigned)(pm & 0xFFFFFFFFull));
        float mresp = dec_f(enc);
        out_maxresp[b] = mresp;
        bool judge = (mresp > y_thr[idx]) || (y_age[idx] < 1.0f);
        bool anyu = ctr[0] > 0;
        sTakeA = (judge || !anyu) ? 1 : 0;
    }
    __syncthreads();

    if (!sTakeA) {
        unsigned long long bB = 0ull;
        for (int c = wid; c < nB; c += 8) {
            int y1 = (int)slab[256 + c];
            int c2 = c + 4;
            bool h2 = c2 < nB;
            int y2 = (int)slab[256 + (h2 ? c2 : c)];
            const float4* w1 = reinterpret_cast<const float4*>(wxw + (size_t)y1 * X_N);
            const float4* w2 = reinterpret_cast<const float4*>(wxw + (size_t)y2 * X_N);
            float d1 = 0.f, d2 = 0.f;
            #pragma unroll
            for (int j = 0; j < 4; ++j) {
                float4 a1 = w1[j * 64 + lane];
                float4 a2 = w2[j * 64 + lane];
                d1 += xv[j].x*a1.x + xv[j].y*a1.y + xv[j].z*a1.z + xv[j].w*a1.w;
                d2 += xv[j].x*a2.x + xv[j].y*a2.y + xv[j].z*a2.z + xv[j].w*a2.w;
            }
            #pragma unroll
            for (int s = 32; s > 0; s >>= 1) {
                d1 += __shfl_xor(d1, s, 64);
                d2 += __shfl_xor(d2, s, 64);
            }
            float v1 = 0.5f*invx*inv_wx[y1]*d1 + 0.5f*inv_wz[y1]*wzw[(size_t)y1*Z_N + zb];
            unsigned long long p1 = pack_vi(v1, y1);
            bB = (p1 > bB) ? p1 : bB;
            if (h2) {
                float v2 = 0.5f*invx*inv_wx[y2]*d2 + 0.5f*inv_wz[y2]*wzw[(size_t)y2*Z_N + zb];
                unsigned long long p2 = pack_vi(v2, y2);
                bB = (p2 > bB) ? p2 : bB;
            }
        }
        if (lane == 0) red[wid] = bB;
    }
    __syncthreads();
    if (t == 0) {
        unsigned long long pm = sPM;
        unsigned enc = (unsigned)(pm >> 32);
        int idx = (int)(0xFFFFFFFFu - (unsigned)(pm & 0xFFFFFFFFull));
        int fin;
        if (sTakeA) {
            fin = idx;
        } else if (nB > 0) {
            unsigned long long pf = red[0];
            #pragma unroll
            for (int j = 1; j < 4; ++j) pf = (red[j] > pf) ? red[j] : pf;
            fin = (int)(0xFFFFFFFFu - (unsigned)(pf & 0xFFFFFFFFull));
        } else {
            fin = ctr[2];
        }
        final_idx[b] = fin;
        atomicAdd(&cnt[fin], 1);
        atomicMin(&segmin[fin], enc);
        atomicAdd(&zcnt[zb], 1);
    }
}

__global__ __launch_bounds__(256) void wx_out_kernel(
    const float* __restrict__ wxw, const float* __restrict__ inv_wx,
    const float* __restrict__ x, const float* __restrict__ inv_x,
    const int* __restrict__ final_idx, const int* __restrict__ cnt,
    const float* __restrict__ y_age, float* __restrict__ outw) {
    int j = blockIdx.x;
    int t = threadIdx.x;
    __shared__ int s_b[1024];
    __shared__ int s_n;
    if (t == 0) s_n = 0;
    __syncthreads();
    int c = cnt[j];
    if (c > 0) {
        for (int b = t; b < B_N; b += 256)
            if (final_idx[b] == j) { int p = atomicAdd(&s_n, 1); s_b[p] = b; }
    }
    __syncthreads();
    float inv = inv_wx[j];
    float lr = 1.0f / (y_age[j] + 1.0f);
    float fc = (float)c;
    float dv = (c > 0) ? fc : 1.0f;
    int n = s_n;
    float4 w = *reinterpret_cast<const float4*>(wxw + (size_t)j * X_N + t * 4);
    float4 wn = make_float4(w.x*inv, w.y*inv, w.z*inv, w.w*inv);
    if (c > 0) {
        float4 s = make_float4(0.f, 0.f, 0.f, 0.f);
        for (int m = 0; m < n; ++m) {
            int b = s_b[m];
            float ix = inv_x[b];
            float4 xv = *reinterpret_cast<const float4*>(x + (size_t)b * X_N + t * 4);
            s.x += xv.x * ix; s.y += xv.y * ix; s.z += xv.z * ix; s.w += xv.w * ix;
        }
        float f = lr / dv;
        wn.x += f * (s.x - fc * wn.x);
        wn.y += f * (s.y - fc * wn.y);
        wn.z += f * (s.z - fc * wn.z);
        wn.w += f * (s.w - fc * wn.w);
    }
    *reinterpret_cast<float4*>(outw + (size_t)j * X_N + t * 4) = wn;
}

__global__ __launch_bounds__(256) void wz_out_kernel(
    const float* __restrict__ wzw, const float* __restrict__ inv_wz,
    const int* __restrict__ zlab, const int* __restrict__ final_idx,
    const int* __restrict__ cnt, const float* __restrict__ y_age,
    float* __restrict__ outw) {
    int j = blockIdx.x;
    int t = threadIdx.x;
    __shared__ int s_c[1024];
    __shared__ int s_n;
    if (t == 0) s_n = 0;
    __syncthreads();
    int c = cnt[j];
    if (c > 0) {
        for (int b = t; b < B_N; b += 256)
            if (final_idx[b] == j) { int p = atomicAdd(&s_n, 1); s_c[p] = zlab[b]; }
    }
    __syncthreads();
    if (t >= 250) return;
    float inv = inv_wz[j];
    float lr = 1.0f / (y_age[j] + 1.0f);
    float fc = (float)c;
    float dv = (c > 0) ? fc : 1.0f;
    int n = s_n;
    float4 w = *reinterpret_cast<const float4*>(wzw + (size_t)j * Z_N + t * 4);
    float4 wn = make_float4(w.x*inv, w.y*inv, w.z*inv, w.w*inv);
    if (c > 0) {
        float4 s = make_float4(0.f, 0.f, 0.f, 0.f);
        for (int m = 0; m < n; ++m) {
            int d = s_c[m] - t * 4;
            if (d == 0) s.x += 1.f;
            else if (d == 1) s.y += 1.f;
            else if (d == 2) s.z += 1.f;
            else if (d == 3) s.w += 1.f;
        }
        float f = lr / dv;
        wn.x += f * (s.x - fc * wn.x);
        wn.y += f * (s.y - fc * wn.y);
        wn.z += f * (s.z - fc * wn.z);
        wn.w += f * (s.w - fc * wn.w);
    }
    *reinterpret_cast<float4*>(outw + (size_t)j * Z_N + t * 4) = wn;
}

// fused: row-norm of U + U update (row held in registers; one read, one write)
__global__ __launch_bounds__(256) void u_out_kernel(
    const float* __restrict__ uw, const int* __restrict__ zlab,
    const int* __restrict__ final_idx, const int* __restrict__ zcnt,
    const float* __restrict__ z_age, float* __restrict__ outw) {
    int cz = blockIdx.x;
    int t = threadIdx.x;
    const int lane = t & 63, wid = t >> 6;
    __shared__ int s_w[1024];
    __shared__ int s_n;
    __shared__ float rss[4];
    if (t == 0) s_n = 0;

    const float4* rowp4 = reinterpret_cast<const float4*>(uw + (size_t)cz * Y_N);
    float4 u[16];
    float ss = 0.f;
    #pragma unroll
    for (int p = 0; p < 16; ++p) {
        u[p] = rowp4[p * 256 + t];
        ss += u[p].x*u[p].x + u[p].y*u[p].y + u[p].z*u[p].z + u[p].w*u[p].w;
    }
    #pragma unroll
    for (int s = 32; s > 0; s >>= 1) ss += __shfl_xor(ss, s, 64);
    if (lane == 0) rss[wid] = ss;
    __syncthreads();
    float inv = 1.0f / fmaxf(sqrtf(rss[0] + rss[1] + rss[2] + rss[3]), 1e-12f);

    int c = zcnt[cz];
    if (c > 0) {
        for (int b = t; b < B_N; b += 256)
            if (zlab[b] == cz) { int p = atomicAdd(&s_n, 1); s_w[p] = final_idx[b]; }
    }
    __syncthreads();
    float zlr = 1.0f / (z_age[cz] + 1.0f);
    float fc = (float)c;
    float dv = (c > 0) ? fc : 1.0f;
    float f = zlr / dv;
    int n = s_n;
    float* outp = outw + (size_t)cz * Y_N;
    #pragma unroll
    for (int p = 0; p < 16; ++p) {
        int e4 = p * 256 + t;
        float4 un = make_float4(u[p].x*inv, u[p].y*inv, u[p].z*inv, u[p].w*inv);
        if (c > 0) {
            float4 s = make_float4(0.f, 0.f, 0.f, 0.f);
            for (int m = 0; m < n; ++m) {
                int d = s_w[m] - e4 * 4;
                if (d == 0) s.x += 1.f;
                else if (d == 1) s.y += 1.f;
                else if (d == 2) s.z += 1.f;
                else if (d == 3) s.w += 1.f;
            }
            un.x += f * (s.x - fc * un.x);
            un.y += f * (s.y - fc * un.y);
            un.z += f * (s.z - fc * un.z);
            un.w += f * (s.w - fc * un.w);
        }
        *reinterpret_cast<float4*>(outp + e4 * 4) = un;
    }
}

__global__ void thr_age_kernel(const int* __restrict__ cnt, const unsigned* __restrict__ segmin,
                               const float* __restrict__ y_age, const float* __restrict__ y_thr,
                               float* __restrict__ out_thr, float* __restrict__ out_age,
                               int* ctr) {
    int j = blockIdx.x * 256 + threadIdx.x;
    int c = cnt[j];
    float age = y_age[j];
    float thr = y_thr[j];
    float tn = thr;
    if (c > 0) {
        float lr = 1.0f / (age + 1.0f);
        float smin = dec_f(segmin[j]);
        float ycur = fminf(smin, 3.0f);
        if (ycur > 2.0f) ycur = 0.0f;
        tn = lr * ycur + (1.0f - lr) * thr;
    }
    out_thr[j] = tn;
    float an = age + (float)c;
    out_age[j] = an;
    unsigned long long m = __ballot(an >= 1.0f ? 1 : 0);
    if ((threadIdx.x & 63) == 0) atomicAdd(ctr + 1, (int)__popcll(m));
}

__global__ void zage_act_kernel(const int* __restrict__ zcnt, const float* __restrict__ z_age,
                                const int* __restrict__ ctr, float* __restrict__ out_zage,
                                float* __restrict__ out_act) {
    int i = blockIdx.x * 256 + threadIdx.x;
    if (i < Z_N) out_zage[i] = z_age[i] + (float)zcnt[i];
    if (i == 0) out_act[0] = (float)ctr[1];
}

extern "C" void kernel_launch(void* const* d_in, const int* in_sizes, int n_in,
                              void* d_out, int out_size, void* d_ws, size_t ws_size,
                              hipStream_t stream) {
    const float* x     = (const float*)d_in[0];
    const int*   z     = (const int*)d_in[1];
    const float* wxw   = (const float*)d_in[2];
    const float* wzw   = (const float*)d_in[3];
    const float* uw    = (const float*)d_in[4];
    const float* y_age = (const float*)d_in[5];
    const float* z_age = (const float*)d_in[6];
    const float* y_thr = (const float*)d_in[7];
    float* out = (float*)d_out;
    float* ws  = (float*)d_ws;
    char*  ob  = (char*)d_out;

    float* inv_x  = ws + WS_INV_X;
    float* inv_wx = ws + WS_INV_WX;
    float* inv_wz = ws + WS_INV_WZ;
    int* fidx = (int*)(ws + WS_FIDX);
    int* cnt  = (int*)(ws + WS_CNT);
    int* zcnt = (int*)(ws + WS_ZCNT);
    unsigned* segmin = (unsigned*)(ws + WS_SEGMIN);
    int* ctr = (int*)(ws + WS_CTR);
    unsigned long long* mbits = (unsigned long long*)(ws + WS_MBITS);
    int* ccnt = (int*)(ws + WS_CCNT);

    ushort_t* Bb  = (ushort_t*)(ob + SCR_B_BYTES);
    ushort_t* Sc  = (ushort_t*)(ob + SCR_S_BYTES);
    ushort_t* Ab  = (ushort_t*)(ob + SCR_A_BYTES);
    unsigned* gcand = (unsigned*)(ob + SCR_CAND_BYTES);
    ushort_t* wzt = (ushort_t*)(ob + SCR_WZT_BYTES);

    init_kernel<<<64, 256, 0, stream>>>(cnt, segmin, zcnt, ctr);
    unact_kernel<<<Y_N / 256, 256, 0, stream>>>(y_age, ctr, mbits);
    pack_x_kernel<<<B_N, 256, 0, stream>>>(x, Ab, inv_x);
    pack_w_kernel<<<Y_N, 256, 0, stream>>>(wxw, wzw, Bb, inv_wx, inv_wz);
    wzt_kernel<<<16 * 256, 256, 0, stream>>>(wzw, inv_wz, wzt);
    mm256_kernel<<<(B_N / 256) * (Y_N / 256), 512, 0, stream>>>(Ab, Bb, Sc);
    scan_kernel<<<B_N, 256, 0, stream>>>(Sc, wzt, z, mbits, ctr, gcand, ccnt);
    rescore_kernel<<<B_N, 256, 0, stream>>>(gcand, ccnt, x, inv_x, wxw, inv_wx, wzw, inv_wz,
                                            z, y_thr, y_age, ctr, fidx, cnt, segmin, zcnt,
                                            out + OFF_MAXRESP);
    wx_out_kernel<<<Y_N, 256, 0, stream>>>(wxw, inv_wx, x, inv_x, fidx, cnt, y_age, out + OFF_WX);
    wz_out_kernel<<<Y_N, 256, 0, stream>>>(wzw, inv_wz, z, fidx, cnt, y_age, out + OFF_WZ);
    u_out_kernel<<<Z_N, 256, 0, stream>>>(uw, z, fidx, zcnt, z_age, out + OFF_U);
    thr_age_kernel<<<Y_N / 256, 256, 0, stream>>>(cnt, segmin, y_age, y_thr,
                                                  out + OFF_THR, out + OFF_AGE, ctr);
    zage_act_kernel<<<4, 256, 0, stream>>>(zcnt, z_age, ctr, out + OFF_ZAGE, out + OFF_ACT);
}